// Round 18
// baseline (344.628 us; speedup 1.0000x reference)
//
#include <hip/hip_runtime.h>
#include <math.h>

// Problem constants
#define BB 2
#define QQ 16
#define DD 2048
#define HH 16
#define DHH 128
#define PP 8192
#define FF 5632
#define KK 8208
#define BH 32
#define RR 32      // B*Q rows
#define NPRUNE 820

// Workspace layout (float offsets). ws_size ~512 MiB.
#define OFF_X      0u
#define OFF_QR     65536u
#define OFF_KN     131072u
#define OFF_VN     196608u
#define OFF_ROWM   262144u
#define OFF_ROWZ   262656u
#define OFF_OATTN  263168u
#define OFF_H      328704u
#define OFF_Y      394240u
#define OFF_ACT    459776u
#define OFF_UNION  640064u      // partial region, reused sequentially (r17 audit)
#define OFF_P64P   (OFF_UNION + 12582912u)  // proj64 partials, 4456448 floats
#define OFF_F64    (OFF_P64P + 4456448u)
#define D_X64      0u
#define D_K64      65536u
#define D_Q64      131072u
#define D_M64      135168u
#define D_Z64      135200u
#define D_SC       135232u
#define D_KEYS     397888u
#define OFF_RANK   (OFF_F64 + 812192u)      // 8208 ints
#define OFF_PMAX   (OFF_RANK + 8320u)       // 512*17 floats
#define OFF_PSUM   (OFF_PMAX + 8704u)       // 512*17 floats

#define SENT (-3.0e38f)

// ---------------------------------------------------------------- rmsnorm (f32, norm2)
__global__ __launch_bounds__(256) void rmsnorm_kernel(
    const float* __restrict__ in, const float* __restrict__ w,
    float* __restrict__ out)
{
    int r = blockIdx.x;
    const float* x = in + (size_t)r * DD;
    float ss = 0.f;
    for (int c = threadIdx.x; c < DD; c += 256) { float v = x[c]; ss = fmaf(v, v, ss); }
    __shared__ float red[256];
    red[threadIdx.x] = ss;
    __syncthreads();
    for (int off = 128; off > 0; off >>= 1) {
        if (threadIdx.x < off) red[threadIdx.x] += red[threadIdx.x + off];
        __syncthreads();
    }
    float mean = red[0] / (float)DD;
    float scale = 1.0f / sqrtf(mean + 1e-5f);
    for (int c = threadIdx.x; c < DD; c += 256)
        out[(size_t)r * DD + c] = x[c] * scale * w[c];
}

// ---------------------------------------------------------------- fused: rmsnorm1 (0-31) + rms32mix (32-63)
__global__ __launch_bounds__(256) void fused_rms_kernel(
    const float* __restrict__ in, const float* __restrict__ w,
    float* __restrict__ out32, double* __restrict__ out64)
{
    int bx = blockIdx.x, tid = threadIdx.x;
    __shared__ float red[256];
    __shared__ float bs[16];
    __shared__ float sscale;
    if (bx < 32) {
        int r = bx;
        const float* x = in + (size_t)r * DD;
        float ss = 0.f;
        for (int c = tid; c < DD; c += 256) { float v = x[c]; ss = fmaf(v, v, ss); }
        red[tid] = ss;
        __syncthreads();
        for (int off = 128; off > 0; off >>= 1) {
            if (tid < off) red[tid] += red[tid + off];
            __syncthreads();
        }
        float mean = red[0] / (float)DD;
        float scale = 1.0f / sqrtf(mean + 1e-5f);
        for (int c = tid; c < DD; c += 256)
            out32[(size_t)r * DD + c] = x[c] * scale * w[c];
    } else {
        int r = bx - 32;
        const float* x = in + (size_t)r * DD;
        if (tid < 16) {
            const float* a = x + tid * 128;
            float rr[8];
#pragma unroll
            for (int j = 0; j < 8; ++j) { float v = a[j]; rr[j] = __fmul_rn(v, v); }
            for (int i = 8; i < 128; i += 8) {
#pragma unroll
                for (int j = 0; j < 8; ++j) {
                    float v = a[i + j];
                    rr[j] = __fadd_rn(rr[j], __fmul_rn(v, v));
                }
            }
            float t01 = __fadd_rn(rr[0], rr[1]);
            float t23 = __fadd_rn(rr[2], rr[3]);
            float t45 = __fadd_rn(rr[4], rr[5]);
            float t67 = __fadd_rn(rr[6], rr[7]);
            bs[tid] = __fadd_rn(__fadd_rn(t01, t23), __fadd_rn(t45, t67));
        }
        __syncthreads();
        if (tid == 0) {
            float c[8], d[4], e[2];
#pragma unroll
            for (int i = 0; i < 8; ++i) c[i] = __fadd_rn(bs[2 * i], bs[2 * i + 1]);
#pragma unroll
            for (int i = 0; i < 4; ++i) d[i] = __fadd_rn(c[2 * i], c[2 * i + 1]);
            e[0] = __fadd_rn(d[0], d[1]);
            e[1] = __fadd_rn(d[2], d[3]);
            float s = __fadd_rn(e[0], e[1]);
            float v = __fdiv_rn(s, 2048.0f);
            float ve = __fadd_rn(v, 1e-5f);
            float sq = __fsqrt_rn(ve);
            sscale = __fdiv_rn(1.0f, sq);
        }
        __syncthreads();
        double scd = (double)sscale;
        for (int c = tid; c < DD; c += 256)
            out64[(size_t)r * DD + c] = ((double)x[c] * scd) * (double)w[c];
    }
}

// ---------------------------------------------------------------- 32-row GEMM, 2 cols/thread
template<int DCHUNK>
__global__ __launch_bounds__(256) void gemm32c2(
    const float* __restrict__ A, const float* __restrict__ w0,
    const float* __restrict__ w1, const float* __restrict__ w2,
    float* __restrict__ part, int Kdim, int N, size_t zstride)
{
    int cc = blockIdx.x, kc = blockIdx.y, z = blockIdx.z;
    int tid = threadIdx.x;
    int col0 = cc * 512 + tid;
    int d0 = kc * DCHUNK;
    const float* W = (z == 0) ? w0 : (z == 1) ? w1 : w2;
    __shared__ __align__(16) float xs[32 * DCHUNK];
    for (int i = tid; i < 32 * DCHUNK; i += 256) {
        int r = i / DCHUNK, d = i - r * DCHUNK;
        xs[i] = A[(size_t)r * Kdim + d0 + d];
    }
    __syncthreads();
    float acc0[32], acc1[32];
#pragma unroll
    for (int r = 0; r < 32; ++r) { acc0[r] = 0.f; acc1[r] = 0.f; }
    const float* wp = W + (size_t)d0 * N + col0;
    for (int d = 0; d < DCHUNK; d += 8) {
        float wb0[8], wb1[8];
#pragma unroll
        for (int u = 0; u < 8; ++u) {
            wb0[u] = wp[(size_t)(d + u) * N];
            wb1[u] = wp[(size_t)(d + u) * N + 256];
        }
#pragma unroll
        for (int r = 0; r < 32; ++r) {
            const float4 x0 = *(const float4*)(xs + r * DCHUNK + d);
            const float4 x1 = *(const float4*)(xs + r * DCHUNK + d + 4);
            float a = acc0[r], b = acc1[r];
            a = fmaf(x0.x, wb0[0], a);  b = fmaf(x0.x, wb1[0], b);
            a = fmaf(x0.y, wb0[1], a);  b = fmaf(x0.y, wb1[1], b);
            a = fmaf(x0.z, wb0[2], a);  b = fmaf(x0.z, wb1[2], b);
            a = fmaf(x0.w, wb0[3], a);  b = fmaf(x0.w, wb1[3], b);
            a = fmaf(x1.x, wb0[4], a);  b = fmaf(x1.x, wb1[4], b);
            a = fmaf(x1.y, wb0[5], a);  b = fmaf(x1.y, wb1[5], b);
            a = fmaf(x1.z, wb0[6], a);  b = fmaf(x1.z, wb1[6], b);
            a = fmaf(x1.w, wb0[7], a);  b = fmaf(x1.w, wb1[7], b);
            acc0[r] = a; acc1[r] = b;
        }
    }
    float* dst = part + (size_t)z * zstride;
#pragma unroll
    for (int r = 0; r < 32; ++r) {
        dst[((size_t)(kc * 32 + r)) * N + col0] = acc0[r];
        dst[((size_t)(kc * 32 + r)) * N + col0 + 256] = acc1[r];
    }
}

// ---------------------------------------------------------------- fused: QKV GEMM (0-767) + proj64_part (768-1023)
__global__ __launch_bounds__(256) void fused_qkv_p64_kernel(
    const float* __restrict__ A, const float* __restrict__ wq,
    const float* __restrict__ wk, const float* __restrict__ wv,
    float* __restrict__ part, const double* __restrict__ x64,
    double* __restrict__ p64)
{
    int bx = blockIdx.x, tid = threadIdx.x;
    __shared__ __align__(16) float xs[32 * 32];
    __shared__ double xs64[34 * 64];
    if (bx < 768) {
        int cc = bx & 3, kc = (bx >> 2) & 63, z = bx >> 8;
        int col0 = cc * 512 + tid;
        int d0 = kc * 32;
        const float* W = (z == 0) ? wq : (z == 1) ? wk : wv;
        for (int i = tid; i < 32 * 32; i += 256) {
            int r = i >> 5, d = i & 31;
            xs[i] = A[(size_t)r * DD + d0 + d];
        }
        __syncthreads();
        float acc0[32], acc1[32];
#pragma unroll
        for (int r = 0; r < 32; ++r) { acc0[r] = 0.f; acc1[r] = 0.f; }
        const float* wp = W + (size_t)d0 * DD + col0;
        for (int d = 0; d < 32; d += 8) {
            float wb0[8], wb1[8];
#pragma unroll
            for (int u = 0; u < 8; ++u) {
                wb0[u] = wp[(size_t)(d + u) * DD];
                wb1[u] = wp[(size_t)(d + u) * DD + 256];
            }
#pragma unroll
            for (int r = 0; r < 32; ++r) {
                const float4 x0 = *(const float4*)(xs + r * 32 + d);
                const float4 x1 = *(const float4*)(xs + r * 32 + d + 4);
                float a = acc0[r], b = acc1[r];
                a = fmaf(x0.x, wb0[0], a);  b = fmaf(x0.x, wb1[0], b);
                a = fmaf(x0.y, wb0[1], a);  b = fmaf(x0.y, wb1[1], b);
                a = fmaf(x0.z, wb0[2], a);  b = fmaf(x0.z, wb1[2], b);
                a = fmaf(x0.w, wb0[3], a);  b = fmaf(x0.w, wb1[3], b);
                a = fmaf(x1.x, wb0[4], a);  b = fmaf(x1.x, wb1[4], b);
                a = fmaf(x1.y, wb0[5], a);  b = fmaf(x1.y, wb1[5], b);
                a = fmaf(x1.z, wb0[6], a);  b = fmaf(x1.z, wb1[6], b);
                a = fmaf(x1.w, wb0[7], a);  b = fmaf(x1.w, wb1[7], b);
                acc0[r] = a; acc1[r] = b;
            }
        }
        float* dst = part + (size_t)z * 64 * 65536;
#pragma unroll
        for (int r = 0; r < 32; ++r) {
            dst[((size_t)(kc * 32 + r)) * DD + col0] = acc0[r];
            dst[((size_t)(kc * 32 + r)) * DD + col0 + 256] = acc1[r];
        }
    } else {
        int p = bx - 768;
        int cc = p & 7, kc = p >> 3;
        int col = cc * 256 + tid;
        int d0 = kc * 64;
        for (int i = tid; i < 34 * 64; i += 256) {
            int r = i >> 6, d = i & 63;
            int srcrow = (r < 32) ? r : ((r == 32) ? 15 : 31);
            xs64[i] = x64[(size_t)srcrow * DD + d0 + d];
        }
        __syncthreads();
        double acc[34];
#pragma unroll
        for (int r = 0; r < 34; ++r) acc[r] = 0.0;
        const float* wkp = wk + (size_t)d0 * DD + col;
        const float* wqp = wq + (size_t)d0 * DD + col;
        for (int d = 0; d < 64; d += 4) {
            double wkb[4], wqb[4];
#pragma unroll
            for (int u = 0; u < 4; ++u) {
                wkb[u] = (double)wkp[(size_t)(d + u) * DD];
                wqb[u] = (double)wqp[(size_t)(d + u) * DD];
            }
#pragma unroll
            for (int u = 0; u < 4; ++u) {
#pragma unroll
                for (int r = 0; r < 32; ++r) acc[r] = fma(xs64[r * 64 + d + u], wkb[u], acc[r]);
                acc[32] = fma(xs64[32 * 64 + d + u], wqb[u], acc[32]);
                acc[33] = fma(xs64[33 * 64 + d + u], wqb[u], acc[33]);
            }
        }
#pragma unroll
        for (int r = 0; r < 34; ++r)
            p64[((size_t)kc * 34 + r) * DD + col] = acc[r];
    }
}

// ---------------------------------------------------------------- fused: QKV reduce+RoPE (0-255) + proj64 reduce+RoPE (256-527)
__global__ __launch_bounds__(256) void fused_reduce_kernel(
    const float* __restrict__ part, float* __restrict__ qr,
    float* __restrict__ kn, float* __restrict__ vn,
    const double* __restrict__ p64, double* __restrict__ k64,
    double* __restrict__ q64)
{
    int bx = blockIdx.x, tid = threadIdx.x;
    __shared__ float buf[256];
    __shared__ double dbuf[256];
    if (bx < 256) {
        int r = bx >> 3;
        int b = r >> 4, qi = r & 15;
        int c = (bx & 7) * 256 + tid;
        int h = c >> 7, dh = c & 127, j = dh & 63;
        float invf = (float)exp(-((double)j / 64.0) * log(10000.0));
        float ang = (float)(PP + qi) * invf;
        float sn, cs;
        sincosf(ang, &sn, &cs);
        size_t dsti = (((size_t)(b * HH + h)) * QQ + qi) * DHH + dh;
        for (int mat = 0; mat < 3; ++mat) {
            const float* pm = part + (size_t)mat * 64 * 65536 + (size_t)r * DD + c;
            float sa = 0.f, sb = 0.f;
#pragma unroll 8
            for (int kc = 0; kc < 32; ++kc) {
                sa += pm[(size_t)kc * 32 * DD];
                sb += pm[(size_t)(kc + 32) * 32 * DD];
            }
            float s = sa + sb;
            buf[tid] = s;
            __syncthreads();
            float val;
            if (mat == 2) {
                val = s;
            } else {
                float other = (dh < 64) ? -buf[tid + 64] : buf[tid - 64];
                val = s * cs + other * sn;
            }
            float* dst = (mat == 0) ? qr : (mat == 1) ? kn : vn;
            dst[dsti] = val;
            __syncthreads();
        }
    } else {
        int e = (bx - 256) * 256 + tid;
        int r = e >> 11, col = e & 2047;
        double s = 0.0;
#pragma unroll 8
        for (int kc = 0; kc < 32; ++kc) s += p64[((size_t)kc * 34 + r) * DD + col];
        dbuf[tid] = s;
        __syncthreads();
        int dh = col & 127, j = dh & 63;
        int pos = (r < 32) ? (PP + (r & 15)) : (PP + 15);
        float pf = (float)pow(10000.0, (double)j / 64.0);
        float invf = __fdiv_rn(1.0f, pf);
        float ang = __fmul_rn((float)pos, invf);
        float cs = (float)cos((double)ang);
        float sn = (float)sin((double)ang);
        double outv;
        if (dh < 64) outv = s * (double)cs - dbuf[tid + 64] * (double)sn;
        else         outv = s * (double)cs + dbuf[tid - 64] * (double)sn;
        if (r < 32) k64[(size_t)r * DD + col] = outv;
        else        q64[(size_t)(r - 32) * DD + col] = outv;
    }
}

// ---------------------------------------------------------------- scores + f64 + per-chunk softmax partials
__global__ __launch_bounds__(256) void scores_kernel(
    const float* __restrict__ qr, const float* __restrict__ past_k,
    const float* __restrict__ kn, float* __restrict__ attn,
    const double* __restrict__ q64, const double* __restrict__ k64,
    double* __restrict__ sc64, float* __restrict__ pmax, float* __restrict__ psum)
{
    int bh = blockIdx.x, ch = blockIdx.y;
    int b = bh >> 4, h = bh & 15;
    int tid = threadIdx.x;
    __shared__ __align__(16) float qs[QQ * DHH];
    __shared__ double q64s[DHH];
    __shared__ float swm[4], swz[4];
    for (int i = tid; i < QQ * DHH; i += 256) qs[i] = qr[(size_t)bh * (QQ * DHH) + i];
    if (tid < DHH) q64s[tid] = q64[(size_t)b * DD + h * DHH + tid];
    __syncthreads();

    float lmq[QQ], lzq[QQ];
    if (ch < 16) {
        int kbase = ch * 512;
        const float* kr0 = past_k + ((size_t)bh * PP + kbase + tid) * DHH;
        float acc[2][QQ];
#pragma unroll
        for (int u = 0; u < 2; ++u)
#pragma unroll
            for (int q = 0; q < QQ; ++q) acc[u][q] = 0.f;
        double a64[2] = {0.0, 0.0};

        for (int jb = 0; jb < DHH / 4; jb += 2) {
            float4 kb[2][2];
#pragma unroll
            for (int u = 0; u < 2; ++u) {
                const float4* kp = (const float4*)(kr0 + (size_t)u * 256 * DHH);
                kb[u][0] = kp[jb];
                kb[u][1] = kp[jb + 1];
            }
#pragma unroll
            for (int jj = 0; jj < 2; ++jj) {
#pragma unroll
                for (int q = 0; q < QQ; ++q) {
                    float4 qv = *(const float4*)(qs + q * DHH + (jb + jj) * 4);
#pragma unroll
                    for (int u = 0; u < 2; ++u) {
                        acc[u][q] = fmaf(kb[u][jj].x, qv.x, acc[u][q]);
                        acc[u][q] = fmaf(kb[u][jj].y, qv.y, acc[u][q]);
                        acc[u][q] = fmaf(kb[u][jj].z, qv.z, acc[u][q]);
                        acc[u][q] = fmaf(kb[u][jj].w, qv.w, acc[u][q]);
                    }
                }
            }
#pragma unroll
            for (int jj = 0; jj < 2; ++jj) {
                int j = jb + jj;
#pragma unroll
                for (int u = 0; u < 2; ++u) {
                    a64[u] = fma((double)kb[u][jj].x, q64s[j * 4 + 0], a64[u]);
                    a64[u] = fma((double)kb[u][jj].y, q64s[j * 4 + 1], a64[u]);
                    a64[u] = fma((double)kb[u][jj].z, q64s[j * 4 + 2], a64[u]);
                    a64[u] = fma((double)kb[u][jj].w, q64s[j * 4 + 3], a64[u]);
                }
            }
        }
#pragma unroll
        for (int q = 0; q < QQ; ++q) {
            float sv0 = acc[0][q] / 11.313708498984761f;   // past keys: never masked
            float sv1 = acc[1][q] / 11.313708498984761f;
            attn[((size_t)(bh * QQ + q)) * KK + kbase + tid] = sv0;
            attn[((size_t)(bh * QQ + q)) * KK + kbase + 256 + tid] = sv1;
            float lm = fmaxf(sv0, sv1);
            lmq[q] = lm;
            lzq[q] = expf(sv0 - lm) + expf(sv1 - lm);
        }
#pragma unroll
        for (int u = 0; u < 2; ++u)
            sc64[(size_t)bh * KK + kbase + u * 256 + tid] = a64[u] / (double)sqrtf(128.0f);
    } else {
#pragma unroll
        for (int q = 0; q < QQ; ++q) { lmq[q] = SENT; lzq[q] = 0.f; }
        if (tid < 16) {
            const float* krow = kn + ((size_t)bh * QQ + tid) * DHH;
            float acc[QQ];
#pragma unroll
            for (int q = 0; q < QQ; ++q) acc[q] = 0.f;
            for (int j = 0; j < DHH / 4; ++j) {
                float4 kv = ((const float4*)krow)[j];
#pragma unroll
                for (int q = 0; q < QQ; ++q) {
                    float4 qv = *(const float4*)(qs + q * DHH + j * 4);
                    acc[q] = fmaf(kv.x, qv.x, acc[q]);
                    acc[q] = fmaf(kv.y, qv.y, acc[q]);
                    acc[q] = fmaf(kv.z, qv.z, acc[q]);
                    acc[q] = fmaf(kv.w, qv.w, acc[q]);
                }
            }
            int key = PP + tid;
#pragma unroll
            for (int q = 0; q < QQ; ++q) {
                float sv = acc[q] / 11.313708498984761f;
                if (key > PP + q) sv += -1e9f;
                attn[((size_t)(bh * QQ + q)) * KK + key] = sv;
                lmq[q] = sv;
                lzq[q] = 1.f;
            }
            double a64 = 0.0;
            const double* kd = k64 + (size_t)(b * QQ + tid) * DD + h * DHH;
            for (int j = 0; j < DHH; ++j) a64 = fma(kd[j], q64s[j], a64);
            sc64[(size_t)bh * KK + key] = a64 / (double)sqrtf(128.0f);
        }
    }

    // per-(row, chunk) softmax partial: wave butterfly then 4-wave combine
    int wv = tid >> 6, ln = tid & 63;
#pragma unroll 1
    for (int q = 0; q < QQ; ++q) {
        float lm = lmq[q], lz = lzq[q];
        for (int off = 1; off < 64; off <<= 1) {
            float om = __shfl_xor(lm, off, 64);
            float oz = __shfl_xor(lz, off, 64);
            float nm = fmaxf(lm, om);
            lz = lz * expf(lm - nm) + oz * expf(om - nm);
            lm = nm;
        }
        if (ln == 0) { swm[wv] = lm; swz[wv] = lz; }
        __syncthreads();
        if (tid == 0) {
            float m = swm[0], z = swz[0];
#pragma unroll
            for (int w = 1; w < 4; ++w) {
                float nm = fmaxf(m, swm[w]);
                z = z * expf(m - nm) + swz[w] * expf(swm[w] - nm);
                m = nm;
            }
            pmax[(size_t)(bh * QQ + q) * 17 + ch] = m;
            psum[(size_t)(bh * QQ + q) * 17 + ch] = z;
        }
        __syncthreads();
    }
}

// ---------------------------------------------------------------- fused: stats combine (0-1) + rowstats64 (2-33)
__global__ __launch_bounds__(256) void fused_rowstats_kernel(
    const float* __restrict__ pmax, const float* __restrict__ psum,
    float* __restrict__ rowm, float* __restrict__ rowz,
    const double* __restrict__ sc, double* __restrict__ m64, double* __restrict__ z64)
{
    int bx = blockIdx.x, tid = threadIdx.x;
    __shared__ double dm[256], dz[256];
    if (bx < 2) {
        int row = bx * 256 + tid;
        float m = SENT, z = 0.f;
#pragma unroll
        for (int ch = 0; ch < 17; ++ch) {
            float pm = pmax[(size_t)row * 17 + ch];
            float pz = psum[(size_t)row * 17 + ch];
            float nm = fmaxf(m, pm);
            z = z * expf(m - nm) + pz * expf(pm - nm);
            m = nm;
        }
        rowm[row] = m;
        rowz[row] = z;
    } else {
        int row = bx - 2;
        const double* s = sc + (size_t)row * KK;
        double m = -INFINITY, z = 0.0;
        for (int k = tid; k < KK; k += 256) {
            double v = s[k];
            double nm = fmax(m, v);
            z = z * exp(m - nm) + exp(v - nm);
            m = nm;
        }
        dm[tid] = m; dz[tid] = z;
        __syncthreads();
        for (int off = 128; off > 0; off >>= 1) {
            if (tid < off) {
                double m1 = dm[tid], z1 = dz[tid];
                double m2 = dm[tid + off], z2 = dz[tid + off];
                double nm = fmax(m1, m2);
                dm[tid] = nm;
                dz[tid] = z1 * exp(m1 - nm) + z2 * exp(m2 - nm);
            }
            __syncthreads();
        }
        if (tid == 0) { m64[row] = dm[0]; z64[row] = dz[0]; }
    }
}

// ---------------------------------------------------------------- fused: PV (0-1055) + impkeys (1056-1088)
__global__ __launch_bounds__(256) void fused_pv_impkeys_kernel(
    float* __restrict__ attn, const float* __restrict__ past_v,
    const float* __restrict__ vn, const float* __restrict__ rowm,
    const float* __restrict__ rowz, float* __restrict__ part,
    const double* __restrict__ sc, const double* __restrict__ m64,
    const double* __restrict__ z64, unsigned long long* __restrict__ keys,
    int* __restrict__ rank)
{
    int bx = blockIdx.x, tid = threadIdx.x;
    __shared__ __align__(16) float p[QQ * 256];
    if (bx < 1056) {
        int bh = bx / 33, ch = bx - bh * 33;
        int nk = (ch < 32) ? 256 : 16;
        int kbase = ch * 256;
        if (tid < nk) {
            float sv[QQ];
#pragma unroll
            for (int q = 0; q < QQ; ++q)
                sv[q] = attn[((size_t)(bh * QQ + q)) * KK + kbase + tid];
#pragma unroll
            for (int q = 0; q < QQ; ++q) {
                int row = bh * QQ + q;
                float pv = expf(sv[q] - rowm[row]) / rowz[row];
                attn[((size_t)row) * KK + kbase + tid] = pv;
                p[q * 256 + tid] = pv;
            }
        }
        __syncthreads();

        int dq = tid & 31, q0 = tid >> 5;
        int d4 = dq * 4;
        float4 a0 = make_float4(0, 0, 0, 0), a1 = make_float4(0, 0, 0, 0);
        if (ch < 32) {
            const float* vbase = past_v + ((size_t)bh * PP + kbase) * DHH;
            for (int kk = 0; kk < 256; kk += 8) {
                float4 vb[8];
#pragma unroll
                for (int u = 0; u < 8; ++u)
                    vb[u] = *(const float4*)(vbase + (size_t)(kk + u) * DHH + d4);
#pragma unroll
                for (int u = 0; u < 8; ++u) {
                    float p0 = p[q0 * 256 + kk + u];
                    float p1 = p[(q0 + 8) * 256 + kk + u];
                    a0.x = fmaf(vb[u].x, p0, a0.x); a0.y = fmaf(vb[u].y, p0, a0.y);
                    a0.z = fmaf(vb[u].z, p0, a0.z); a0.w = fmaf(vb[u].w, p0, a0.w);
                    a1.x = fmaf(vb[u].x, p1, a1.x); a1.y = fmaf(vb[u].y, p1, a1.y);
                    a1.z = fmaf(vb[u].z, p1, a1.z); a1.w = fmaf(vb[u].w, p1, a1.w);
                }
            }
        } else {
            const float* vbase = vn + (size_t)bh * QQ * DHH;
            for (int kk = 0; kk < 16; ++kk) {
                float4 v4 = *(const float4*)(vbase + (size_t)kk * DHH + d4);
                float p0 = p[q0 * 256 + kk];
                float p1 = p[(q0 + 8) * 256 + kk];
                a0.x = fmaf(v4.x, p0, a0.x); a0.y = fmaf(v4.y, p0, a0.y);
                a0.z = fmaf(v4.z, p0, a0.z); a0.w = fmaf(v4.w, p0, a0.w);
                a1.x = fmaf(v4.x, p1, a1.x); a1.y = fmaf(v4.y, p1, a1.y);
                a1.z = fmaf(v4.z, p1, a1.z); a1.w = fmaf(v4.w, p1, a1.w);
            }
        }
        size_t pb = ((size_t)ch * BH + bh) * (QQ * DHH);
        *(float4*)(part + pb + q0 * DHH + d4) = a0;
        *(float4*)(part + pb + (q0 + 8) * DHH + d4) = a1;
    } else {
        int k = (bx - 1056) * 256 + tid;
        if (k >= KK) return;
        rank[k] = 0;
        double t = 0.0;
        for (int bh = 0; bh < BH; ++bh)
            t += exp(sc[(size_t)bh * KK + k] - m64[bh]) / z64[bh];
        double imp = t / 32.0;
        if (k == KK - 1) imp = INFINITY;
        unsigned long long bits = (unsigned long long)__double_as_longlong(imp);
        keys[k] = (bits & ~0x3FFFull) | (unsigned long long)k;
    }
}

// ---------------------------------------------------------------- fused: PV reduce (0-255) + rankpart (256-519)
__global__ __launch_bounds__(256) void fused_pvred_rankpart_kernel(
    const float* __restrict__ part, float* __restrict__ oattn,
    const unsigned long long* __restrict__ keys, int* __restrict__ rank)
{
    int bx = blockIdx.x, tid = threadIdx.x;
    __shared__ unsigned long long chnk[1026];
    if (bx < 256) {
        int e = bx * 256 + tid;
        float sa = 0.f, sb = 0.f;
#pragma unroll 8
        for (int ch = 0; ch < 16; ++ch) sa += part[(size_t)ch * 65536 + e];
#pragma unroll 8
        for (int ch = 16; ch < 33; ++ch) sb += part[(size_t)ch * 65536 + e];
        float s = sa + sb;
        int bh = e >> 11, rem = e & 2047, q = rem >> 7, d = rem & 127;
        int b = bh >> 4, h = bh & 15;
        oattn[((size_t)(b * QQ + q)) * DD + h * DHH + d] = s;
    } else {
        int idx = bx - 256;
        int xb = idx % 33, yb = idx / 33;
        int gid = xb * 256 + tid;
        int base = yb * 1026;
        for (int i = tid; i < 1026; i += 256) chnk[i] = keys[base + i];
        __syncthreads();
        if (gid >= KK) return;
        unsigned long long mykey = keys[gid];
        int cnt = 0;
#pragma unroll 6
        for (int i = 0; i < 1026; ++i) cnt += (chnk[i] < mykey) ? 1 : 0;
        atomicAdd(&rank[gid], cnt);
    }
}

// ---------------------------------------------------------------- fused: Wo GEMM (0-255) + rankwrite (256-288)
__global__ __launch_bounds__(256) void fused_wogemm_rankwrite_kernel(
    const float* __restrict__ A, const float* __restrict__ wo,
    float* __restrict__ part,
    const unsigned long long* __restrict__ keys, const int* __restrict__ rank,
    float* __restrict__ outp)
{
    int bx = blockIdx.x, tid = threadIdx.x;
    __shared__ __align__(16) float xs[32 * 32];
    if (bx < 256) {
        int cc = bx & 3, kc = bx >> 2;
        int col0 = cc * 512 + tid;
        int d0 = kc * 32;
        for (int i = tid; i < 32 * 32; i += 256) {
            int r = i >> 5, d = i & 31;
            xs[i] = A[(size_t)r * DD + d0 + d];
        }
        __syncthreads();
        float acc0[32], acc1[32];
#pragma unroll
        for (int r = 0; r < 32; ++r) { acc0[r] = 0.f; acc1[r] = 0.f; }
        const float* wp = wo + (size_t)d0 * DD + col0;
        for (int d = 0; d < 32; d += 8) {
            float wb0[8], wb1[8];
#pragma unroll
            for (int u = 0; u < 8; ++u) {
                wb0[u] = wp[(size_t)(d + u) * DD];
                wb1[u] = wp[(size_t)(d + u) * DD + 256];
            }
#pragma unroll
            for (int r = 0; r < 32; ++r) {
                const float4 x0 = *(const float4*)(xs + r * 32 + d);
                const float4 x1 = *(const float4*)(xs + r * 32 + d + 4);
                float a = acc0[r], b = acc1[r];
                a = fmaf(x0.x, wb0[0], a);  b = fmaf(x0.x, wb1[0], b);
                a = fmaf(x0.y, wb0[1], a);  b = fmaf(x0.y, wb1[1], b);
                a = fmaf(x0.z, wb0[2], a);  b = fmaf(x0.z, wb1[2], b);
                a = fmaf(x0.w, wb0[3], a);  b = fmaf(x0.w, wb1[3], b);
                a = fmaf(x1.x, wb0[4], a);  b = fmaf(x1.x, wb1[4], b);
                a = fmaf(x1.y, wb0[5], a);  b = fmaf(x1.y, wb1[5], b);
                a = fmaf(x1.z, wb0[6], a);  b = fmaf(x1.z, wb1[6], b);
                a = fmaf(x1.w, wb0[7], a);  b = fmaf(x1.w, wb1[7], b);
                acc0[r] = a; acc1[r] = b;
            }
        }
#pragma unroll
        for (int r = 0; r < 32; ++r) {
            part[((size_t)(kc * 32 + r)) * DD + col0] = acc0[r];
            part[((size_t)(kc * 32 + r)) * DD + col0 + 256] = acc1[r];
        }
    } else {
        int gid = (bx - 256) * 256 + tid;
        if (gid >= KK) return;
        int r = rank[gid];
        if (r < NPRUNE)
            outp[r] = (float)(unsigned)(keys[gid] & 0x3FFFu);
    }
}

// ---------------------------------------------------------------- Wo reduce + residual (dual 32+32)
__global__ __launch_bounds__(256) void reduce_wo_kernel(
    const float* __restrict__ part, const float* __restrict__ resid,
    float* __restrict__ hbuf)
{
    int e = blockIdx.x * 256 + threadIdx.x;
    float sa = 0.f, sb = 0.f;
#pragma unroll 8
    for (int kc = 0; kc < 32; ++kc) {
        sa += part[(size_t)kc * 65536 + e];
        sb += part[(size_t)(kc + 32) * 65536 + e];
    }
    hbuf[e] = resid[e] + (sa + sb);
}

// ---------------------------------------------------------------- fused gate+up reduce + silu
__global__ __launch_bounds__(256) void reduce_gateup_silu_kernel(
    const float* __restrict__ part, float* __restrict__ act)
{
    int e = blockIdx.x * 256 + threadIdx.x;
    float ga = 0.f, gb = 0.f, ua = 0.f, ub = 0.f;
#pragma unroll 8
    for (int kc = 0; kc < 16; ++kc) {
        ga += part[(size_t)kc * 180224 + e];
        gb += part[(size_t)(kc + 16) * 180224 + e];
        ua += part[(size_t)(kc + 32) * 180224 + e];
        ub += part[(size_t)(kc + 48) * 180224 + e];
    }
    float g = ga + gb, u = ua + ub;
    float sg = g / (1.f + expf(-g));
    act[e] = sg * u;
}

// ---------------------------------------------------------------- down reduce + residual (dual 88+88)
__global__ __launch_bounds__(256) void reduce_down_kernel(
    const float* __restrict__ part, const float* __restrict__ hbuf,
    float* __restrict__ out)
{
    int e = blockIdx.x * 256 + threadIdx.x;
    float sa = 0.f, sb = 0.f;
#pragma unroll 8
    for (int kc = 0; kc < 88; ++kc) {
        sa += part[(size_t)kc * 65536 + e];
        sb += part[(size_t)(kc + 88) * 65536 + e];
    }
    out[e] = hbuf[e] + (sa + sb);
}

// ================================================================ launch
extern "C" void kernel_launch(void* const* d_in, const int* in_sizes, int n_in,
                              void* d_out, int out_size, void* d_ws, size_t ws_size,
                              hipStream_t stream)
{
    const float* hidden = (const float*)d_in[0];
    const float* past_k = (const float*)d_in[1];
    const float* past_v = (const float*)d_in[2];
    const float* wq     = (const float*)d_in[3];
    const float* wk     = (const float*)d_in[4];
    const float* wv     = (const float*)d_in[5];
    const float* wo     = (const float*)d_in[6];
    const float* wgate  = (const float*)d_in[7];
    const float* wup    = (const float*)d_in[8];
    const float* wdown  = (const float*)d_in[9];
    const float* n1w    = (const float*)d_in[10];
    const float* n2w    = (const float*)d_in[11];

    float* out_hidden = (float*)d_out;
    float* attn = out_hidden + (size_t)RR * DD;
    float* out_prune = attn + (size_t)BH * QQ * KK;
    float* ws = (float*)d_ws;
    double* p64part = (double*)(ws + OFF_P64P);
    double* f64 = (double*)(ws + OFF_F64);
    double* x64 = f64 + D_X64;
    double* k64 = f64 + D_K64;
    double* q64 = f64 + D_Q64;
    double* m64 = f64 + D_M64;
    double* z64 = f64 + D_Z64;
    double* sc64 = f64 + D_SC;
    unsigned long long* keys = (unsigned long long*)(f64 + D_KEYS);
    int* rank = (int*)(ws + OFF_RANK);
    float* pmax = ws + OFF_PMAX;
    float* psum = ws + OFF_PSUM;

    // 1. rmsnorm1 + rms32mix
    fused_rms_kernel<<<dim3(64), dim3(256), 0, stream>>>(hidden, n1w, ws + OFF_X, x64);

    // 2. QKV GEMM + proj64_part
    fused_qkv_p64_kernel<<<dim3(1024), dim3(256), 0, stream>>>(
        ws + OFF_X, wq, wk, wv, ws + OFF_UNION, x64, p64part);

    // 3. QKV reduce+RoPE + proj64 reduce+RoPE
    fused_reduce_kernel<<<dim3(528), dim3(256), 0, stream>>>(
        ws + OFF_UNION, ws + OFF_QR, ws + OFF_KN, ws + OFF_VN, p64part, k64, q64);

    // 4. scores (+ f64 + softmax partials)
    scores_kernel<<<dim3(BH, 17), dim3(256), 0, stream>>>(
        ws + OFF_QR, past_k, ws + OFF_KN, attn, q64, k64, sc64, pmax, psum);

    // 5. stats combine (2) + rowstats64 (32)
    fused_rowstats_kernel<<<dim3(34), dim3(256), 0, stream>>>(
        pmax, psum, ws + OFF_ROWM, ws + OFF_ROWZ, sc64, m64, z64);

    // 6. PV + impkeys
    fused_pv_impkeys_kernel<<<dim3(1089), dim3(256), 0, stream>>>(
        attn, past_v, ws + OFF_VN, ws + OFF_ROWM, ws + OFF_ROWZ, ws + OFF_UNION,
        sc64, m64, z64, keys, rank);

    // 7. PV reduce + rankpart
    fused_pvred_rankpart_kernel<<<dim3(520), dim3(256), 0, stream>>>(
        ws + OFF_UNION, ws + OFF_OATTN, keys, rank);

    // 8. Wo GEMM + rankwrite
    fused_wogemm_rankwrite_kernel<<<dim3(289), dim3(256), 0, stream>>>(
        ws + OFF_OATTN, wo, ws + OFF_UNION, keys, rank, out_prune);

    // 9. + residual
    reduce_wo_kernel<<<dim3(256), dim3(256), 0, stream>>>(ws + OFF_UNION, hidden, ws + OFF_H);

    // 10. rmsnorm2
    rmsnorm_kernel<<<dim3(RR), dim3(256), 0, stream>>>(ws + OFF_H, n2w, ws + OFF_Y);

    // 11. gate+up GEMM + fused reduce+silu
    gemm32c2<64><<<dim3(11, 32, 2), dim3(256), 0, stream>>>(
        ws + OFF_Y, wgate, wup, wup, ws + OFF_UNION, DD, FF, (size_t)32 * 180224);
    reduce_gateup_silu_kernel<<<dim3(704), dim3(256), 0, stream>>>(
        ws + OFF_UNION, ws + OFF_ACT);

    // 12. down GEMM + reduce
    gemm32c2<32><<<dim3(4, 176, 1), dim3(256), 0, stream>>>(
        ws + OFF_ACT, wdown, wdown, wdown, ws + OFF_UNION, FF, DD, 0);
    reduce_down_kernel<<<dim3(256), dim3(256), 0, stream>>>(
        ws + OFF_UNION, ws + OFF_H, out_hidden);
}

// Round 19
// 329.514 us; speedup vs baseline: 1.0459x; 1.0459x over previous
//
#include <hip/hip_runtime.h>
#include <math.h>

// Problem constants
#define BB 2
#define QQ 16
#define DD 2048
#define HH 16
#define DHH 128
#define PP 8192
#define FF 5632
#define KK 8208
#define BH 32
#define RR 32      // B*Q rows
#define NPRUNE 820

// Workspace layout (float offsets). ws_size ~512 MiB.
#define OFF_X      0u
#define OFF_QR     65536u
#define OFF_KN     131072u
#define OFF_VN     196608u
#define OFF_ROWM   262144u
#define OFF_ROWZ   262656u
#define OFF_OATTN  263168u
#define OFF_H      328704u
#define OFF_Y      394240u
#define OFF_ACT    459776u
#define OFF_UNION  640064u      // partial region, reused sequentially (r17 audit)
#define OFF_P64P   (OFF_UNION + 12582912u)  // proj64 partials, 4456448 floats
#define OFF_F64    (OFF_P64P + 4456448u)
#define D_X64      0u
#define D_K64      65536u
#define D_Q64      131072u
#define D_M64      135168u
#define D_Z64      135200u
#define D_SC       135232u
#define D_KEYS     397888u
#define OFF_RANK   (OFF_F64 + 812192u)      // 8208 ints
#define OFF_PMAX   (OFF_RANK + 8320u)       // 512*17 floats
#define OFF_PSUM   (OFF_PMAX + 8704u)       // 512*17 floats

#define SENT (-3.0e38f)

// ---------------------------------------------------------------- rmsnorm (f32, norm2)
__global__ __launch_bounds__(256) void rmsnorm_kernel(
    const float* __restrict__ in, const float* __restrict__ w,
    float* __restrict__ out)
{
    int r = blockIdx.x;
    const float* x = in + (size_t)r * DD;
    float ss = 0.f;
    for (int c = threadIdx.x; c < DD; c += 256) { float v = x[c]; ss = fmaf(v, v, ss); }
    __shared__ float red[256];
    red[threadIdx.x] = ss;
    __syncthreads();
    for (int off = 128; off > 0; off >>= 1) {
        if (threadIdx.x < off) red[threadIdx.x] += red[threadIdx.x + off];
        __syncthreads();
    }
    float mean = red[0] / (float)DD;
    float scale = 1.0f / sqrtf(mean + 1e-5f);
    for (int c = threadIdx.x; c < DD; c += 256)
        out[(size_t)r * DD + c] = x[c] * scale * w[c];
}

// ---------------------------------------------------------------- fused: rmsnorm1 (0-31) + rms32mix (32-63)
__global__ __launch_bounds__(256) void fused_rms_kernel(
    const float* __restrict__ in, const float* __restrict__ w,
    float* __restrict__ out32, double* __restrict__ out64)
{
    int bx = blockIdx.x, tid = threadIdx.x;
    __shared__ float red[256];
    __shared__ float bs[16];
    __shared__ float sscale;
    if (bx < 32) {
        int r = bx;
        const float* x = in + (size_t)r * DD;
        float ss = 0.f;
        for (int c = tid; c < DD; c += 256) { float v = x[c]; ss = fmaf(v, v, ss); }
        red[tid] = ss;
        __syncthreads();
        for (int off = 128; off > 0; off >>= 1) {
            if (tid < off) red[tid] += red[tid + off];
            __syncthreads();
        }
        float mean = red[0] / (float)DD;
        float scale = 1.0f / sqrtf(mean + 1e-5f);
        for (int c = tid; c < DD; c += 256)
            out32[(size_t)r * DD + c] = x[c] * scale * w[c];
    } else {
        int r = bx - 32;
        const float* x = in + (size_t)r * DD;
        if (tid < 16) {
            const float* a = x + tid * 128;
            float rr[8];
#pragma unroll
            for (int j = 0; j < 8; ++j) { float v = a[j]; rr[j] = __fmul_rn(v, v); }
            for (int i = 8; i < 128; i += 8) {
#pragma unroll
                for (int j = 0; j < 8; ++j) {
                    float v = a[i + j];
                    rr[j] = __fadd_rn(rr[j], __fmul_rn(v, v));
                }
            }
            float t01 = __fadd_rn(rr[0], rr[1]);
            float t23 = __fadd_rn(rr[2], rr[3]);
            float t45 = __fadd_rn(rr[4], rr[5]);
            float t67 = __fadd_rn(rr[6], rr[7]);
            bs[tid] = __fadd_rn(__fadd_rn(t01, t23), __fadd_rn(t45, t67));
        }
        __syncthreads();
        if (tid == 0) {
            float c[8], d[4], e[2];
#pragma unroll
            for (int i = 0; i < 8; ++i) c[i] = __fadd_rn(bs[2 * i], bs[2 * i + 1]);
#pragma unroll
            for (int i = 0; i < 4; ++i) d[i] = __fadd_rn(c[2 * i], c[2 * i + 1]);
            e[0] = __fadd_rn(d[0], d[1]);
            e[1] = __fadd_rn(d[2], d[3]);
            float s = __fadd_rn(e[0], e[1]);
            float v = __fdiv_rn(s, 2048.0f);
            float ve = __fadd_rn(v, 1e-5f);
            float sq = __fsqrt_rn(ve);
            sscale = __fdiv_rn(1.0f, sq);
        }
        __syncthreads();
        double scd = (double)sscale;
        for (int c = tid; c < DD; c += 256)
            out64[(size_t)r * DD + c] = ((double)x[c] * scd) * (double)w[c];
    }
}

// ---------------------------------------------------------------- 32-row GEMM, 2 cols/thread
template<int DCHUNK>
__global__ __launch_bounds__(256) void gemm32c2(
    const float* __restrict__ A, const float* __restrict__ w0,
    const float* __restrict__ w1, const float* __restrict__ w2,
    float* __restrict__ part, int Kdim, int N, size_t zstride)
{
    int cc = blockIdx.x, kc = blockIdx.y, z = blockIdx.z;
    int tid = threadIdx.x;
    int col0 = cc * 512 + tid;
    int d0 = kc * DCHUNK;
    const float* W = (z == 0) ? w0 : (z == 1) ? w1 : w2;
    __shared__ __align__(16) float xs[32 * DCHUNK];
    for (int i = tid; i < 32 * DCHUNK; i += 256) {
        int r = i / DCHUNK, d = i - r * DCHUNK;
        xs[i] = A[(size_t)r * Kdim + d0 + d];
    }
    __syncthreads();
    float acc0[32], acc1[32];
#pragma unroll
    for (int r = 0; r < 32; ++r) { acc0[r] = 0.f; acc1[r] = 0.f; }
    const float* wp = W + (size_t)d0 * N + col0;
    for (int d = 0; d < DCHUNK; d += 8) {
        float wb0[8], wb1[8];
#pragma unroll
        for (int u = 0; u < 8; ++u) {
            wb0[u] = wp[(size_t)(d + u) * N];
            wb1[u] = wp[(size_t)(d + u) * N + 256];
        }
#pragma unroll
        for (int r = 0; r < 32; ++r) {
            const float4 x0 = *(const float4*)(xs + r * DCHUNK + d);
            const float4 x1 = *(const float4*)(xs + r * DCHUNK + d + 4);
            float a = acc0[r], b = acc1[r];
            a = fmaf(x0.x, wb0[0], a);  b = fmaf(x0.x, wb1[0], b);
            a = fmaf(x0.y, wb0[1], a);  b = fmaf(x0.y, wb1[1], b);
            a = fmaf(x0.z, wb0[2], a);  b = fmaf(x0.z, wb1[2], b);
            a = fmaf(x0.w, wb0[3], a);  b = fmaf(x0.w, wb1[3], b);
            a = fmaf(x1.x, wb0[4], a);  b = fmaf(x1.x, wb1[4], b);
            a = fmaf(x1.y, wb0[5], a);  b = fmaf(x1.y, wb1[5], b);
            a = fmaf(x1.z, wb0[6], a);  b = fmaf(x1.z, wb1[6], b);
            a = fmaf(x1.w, wb0[7], a);  b = fmaf(x1.w, wb1[7], b);
            acc0[r] = a; acc1[r] = b;
        }
    }
    float* dst = part + (size_t)z * zstride;
#pragma unroll
    for (int r = 0; r < 32; ++r) {
        dst[((size_t)(kc * 32 + r)) * N + col0] = acc0[r];
        dst[((size_t)(kc * 32 + r)) * N + col0 + 256] = acc1[r];
    }
}

// ---------------------------------------------------------------- fused: QKV GEMM (0-767) + proj64_part (768-1023)
__global__ __launch_bounds__(256) void fused_qkv_p64_kernel(
    const float* __restrict__ A, const float* __restrict__ wq,
    const float* __restrict__ wk, const float* __restrict__ wv,
    float* __restrict__ part, const double* __restrict__ x64,
    double* __restrict__ p64)
{
    int bx = blockIdx.x, tid = threadIdx.x;
    __shared__ __align__(16) float xs[32 * 32];
    __shared__ double xs64[34 * 64];
    if (bx < 768) {
        int cc = bx & 3, kc = (bx >> 2) & 63, z = bx >> 8;
        int col0 = cc * 512 + tid;
        int d0 = kc * 32;
        const float* W = (z == 0) ? wq : (z == 1) ? wk : wv;
        for (int i = tid; i < 32 * 32; i += 256) {
            int r = i >> 5, d = i & 31;
            xs[i] = A[(size_t)r * DD + d0 + d];
        }
        __syncthreads();
        float acc0[32], acc1[32];
#pragma unroll
        for (int r = 0; r < 32; ++r) { acc0[r] = 0.f; acc1[r] = 0.f; }
        const float* wp = W + (size_t)d0 * DD + col0;
        for (int d = 0; d < 32; d += 8) {
            float wb0[8], wb1[8];
#pragma unroll
            for (int u = 0; u < 8; ++u) {
                wb0[u] = wp[(size_t)(d + u) * DD];
                wb1[u] = wp[(size_t)(d + u) * DD + 256];
            }
#pragma unroll
            for (int r = 0; r < 32; ++r) {
                const float4 x0 = *(const float4*)(xs + r * 32 + d);
                const float4 x1 = *(const float4*)(xs + r * 32 + d + 4);
                float a = acc0[r], b = acc1[r];
                a = fmaf(x0.x, wb0[0], a);  b = fmaf(x0.x, wb1[0], b);
                a = fmaf(x0.y, wb0[1], a);  b = fmaf(x0.y, wb1[1], b);
                a = fmaf(x0.z, wb0[2], a);  b = fmaf(x0.z, wb1[2], b);
                a = fmaf(x0.w, wb0[3], a);  b = fmaf(x0.w, wb1[3], b);
                a = fmaf(x1.x, wb0[4], a);  b = fmaf(x1.x, wb1[4], b);
                a = fmaf(x1.y, wb0[5], a);  b = fmaf(x1.y, wb1[5], b);
                a = fmaf(x1.z, wb0[6], a);  b = fmaf(x1.z, wb1[6], b);
                a = fmaf(x1.w, wb0[7], a);  b = fmaf(x1.w, wb1[7], b);
                acc0[r] = a; acc1[r] = b;
            }
        }
        float* dst = part + (size_t)z * 64 * 65536;
#pragma unroll
        for (int r = 0; r < 32; ++r) {
            dst[((size_t)(kc * 32 + r)) * DD + col0] = acc0[r];
            dst[((size_t)(kc * 32 + r)) * DD + col0 + 256] = acc1[r];
        }
    } else {
        int p = bx - 768;
        int cc = p & 7, kc = p >> 3;
        int col = cc * 256 + tid;
        int d0 = kc * 64;
        for (int i = tid; i < 34 * 64; i += 256) {
            int r = i >> 6, d = i & 63;
            int srcrow = (r < 32) ? r : ((r == 32) ? 15 : 31);
            xs64[i] = x64[(size_t)srcrow * DD + d0 + d];
        }
        __syncthreads();
        double acc[34];
#pragma unroll
        for (int r = 0; r < 34; ++r) acc[r] = 0.0;
        const float* wkp = wk + (size_t)d0 * DD + col;
        const float* wqp = wq + (size_t)d0 * DD + col;
        for (int d = 0; d < 64; d += 4) {
            double wkb[4], wqb[4];
#pragma unroll
            for (int u = 0; u < 4; ++u) {
                wkb[u] = (double)wkp[(size_t)(d + u) * DD];
                wqb[u] = (double)wqp[(size_t)(d + u) * DD];
            }
#pragma unroll
            for (int u = 0; u < 4; ++u) {
#pragma unroll
                for (int r = 0; r < 32; ++r) acc[r] = fma(xs64[r * 64 + d + u], wkb[u], acc[r]);
                acc[32] = fma(xs64[32 * 64 + d + u], wqb[u], acc[32]);
                acc[33] = fma(xs64[33 * 64 + d + u], wqb[u], acc[33]);
            }
        }
#pragma unroll
        for (int r = 0; r < 34; ++r)
            p64[((size_t)kc * 34 + r) * DD + col] = acc[r];
    }
}

// ---------------------------------------------------------------- fused: QKV reduce+RoPE (0-255) + proj64 reduce+RoPE (256-527)
__global__ __launch_bounds__(256) void fused_reduce_kernel(
    const float* __restrict__ part, float* __restrict__ qr,
    float* __restrict__ kn, float* __restrict__ vn,
    const double* __restrict__ p64, double* __restrict__ k64,
    double* __restrict__ q64)
{
    int bx = blockIdx.x, tid = threadIdx.x;
    __shared__ float buf[256];
    __shared__ double dbuf[256];
    if (bx < 256) {
        int r = bx >> 3;
        int b = r >> 4, qi = r & 15;
        int c = (bx & 7) * 256 + tid;
        int h = c >> 7, dh = c & 127, j = dh & 63;
        float invf = (float)exp(-((double)j / 64.0) * log(10000.0));
        float ang = (float)(PP + qi) * invf;
        float sn, cs;
        sincosf(ang, &sn, &cs);
        size_t dsti = (((size_t)(b * HH + h)) * QQ + qi) * DHH + dh;
        for (int mat = 0; mat < 3; ++mat) {
            const float* pm = part + (size_t)mat * 64 * 65536 + (size_t)r * DD + c;
            float sa = 0.f, sb = 0.f;
#pragma unroll 8
            for (int kc = 0; kc < 32; ++kc) {
                sa += pm[(size_t)kc * 32 * DD];
                sb += pm[(size_t)(kc + 32) * 32 * DD];
            }
            float s = sa + sb;
            buf[tid] = s;
            __syncthreads();
            float val;
            if (mat == 2) {
                val = s;
            } else {
                float other = (dh < 64) ? -buf[tid + 64] : buf[tid - 64];
                val = s * cs + other * sn;
            }
            float* dst = (mat == 0) ? qr : (mat == 1) ? kn : vn;
            dst[dsti] = val;
            __syncthreads();
        }
    } else {
        int e = (bx - 256) * 256 + tid;
        int r = e >> 11, col = e & 2047;
        double s = 0.0;
#pragma unroll 8
        for (int kc = 0; kc < 32; ++kc) s += p64[((size_t)kc * 34 + r) * DD + col];
        dbuf[tid] = s;
        __syncthreads();
        int dh = col & 127, j = dh & 63;
        int pos = (r < 32) ? (PP + (r & 15)) : (PP + 15);
        float pf = (float)pow(10000.0, (double)j / 64.0);
        float invf = __fdiv_rn(1.0f, pf);
        float ang = __fmul_rn((float)pos, invf);
        float cs = (float)cos((double)ang);
        float sn = (float)sin((double)ang);
        double outv;
        if (dh < 64) outv = s * (double)cs - dbuf[tid + 64] * (double)sn;
        else         outv = s * (double)cs + dbuf[tid - 64] * (double)sn;
        if (r < 32) k64[(size_t)r * DD + col] = outv;
        else        q64[(size_t)(r - 32) * DD + col] = outv;
    }
}

// ---------------------------------------------------------------- scores + f64 + cheap per-chunk softmax partials
__global__ __launch_bounds__(256) void scores_kernel(
    const float* __restrict__ qr, const float* __restrict__ past_k,
    const float* __restrict__ kn, float* __restrict__ attn,
    const double* __restrict__ q64, const double* __restrict__ k64,
    double* __restrict__ sc64, float* __restrict__ pmax, float* __restrict__ psum)
{
    int bh = blockIdx.x, ch = blockIdx.y;
    int b = bh >> 4, h = bh & 15;
    int tid = threadIdx.x;
    __shared__ __align__(16) float qs[QQ * DHH];
    __shared__ double q64s[DHH];
    __shared__ float swm[4][QQ], swz[4][QQ];
    for (int i = tid; i < QQ * DHH; i += 256) qs[i] = qr[(size_t)bh * (QQ * DHH) + i];
    if (tid < DHH) q64s[tid] = q64[(size_t)b * DD + h * DHH + tid];
    __syncthreads();

    float lmq[QQ], lzq[QQ];
    if (ch < 16) {
        int kbase = ch * 512;
        const float* kr0 = past_k + ((size_t)bh * PP + kbase + tid) * DHH;
        float acc[2][QQ];
#pragma unroll
        for (int u = 0; u < 2; ++u)
#pragma unroll
            for (int q = 0; q < QQ; ++q) acc[u][q] = 0.f;
        double a64[2] = {0.0, 0.0};

        for (int jb = 0; jb < DHH / 4; jb += 2) {
            float4 kb[2][2];
#pragma unroll
            for (int u = 0; u < 2; ++u) {
                const float4* kp = (const float4*)(kr0 + (size_t)u * 256 * DHH);
                kb[u][0] = kp[jb];
                kb[u][1] = kp[jb + 1];
            }
#pragma unroll
            for (int jj = 0; jj < 2; ++jj) {
#pragma unroll
                for (int q = 0; q < QQ; ++q) {
                    float4 qv = *(const float4*)(qs + q * DHH + (jb + jj) * 4);
#pragma unroll
                    for (int u = 0; u < 2; ++u) {
                        acc[u][q] = fmaf(kb[u][jj].x, qv.x, acc[u][q]);
                        acc[u][q] = fmaf(kb[u][jj].y, qv.y, acc[u][q]);
                        acc[u][q] = fmaf(kb[u][jj].z, qv.z, acc[u][q]);
                        acc[u][q] = fmaf(kb[u][jj].w, qv.w, acc[u][q]);
                    }
                }
            }
#pragma unroll
            for (int jj = 0; jj < 2; ++jj) {
                int j = jb + jj;
#pragma unroll
                for (int u = 0; u < 2; ++u) {
                    a64[u] = fma((double)kb[u][jj].x, q64s[j * 4 + 0], a64[u]);
                    a64[u] = fma((double)kb[u][jj].y, q64s[j * 4 + 1], a64[u]);
                    a64[u] = fma((double)kb[u][jj].z, q64s[j * 4 + 2], a64[u]);
                    a64[u] = fma((double)kb[u][jj].w, q64s[j * 4 + 3], a64[u]);
                }
            }
        }
#pragma unroll
        for (int q = 0; q < QQ; ++q) {
            float sv0 = acc[0][q] / 11.313708498984761f;   // past keys: never masked
            float sv1 = acc[1][q] / 11.313708498984761f;
            attn[((size_t)(bh * QQ + q)) * KK + kbase + tid] = sv0;
            attn[((size_t)(bh * QQ + q)) * KK + kbase + 256 + tid] = sv1;
            float lm = fmaxf(sv0, sv1);
            lmq[q] = lm;
            lzq[q] = expf(sv0 - lm) + expf(sv1 - lm);
        }
#pragma unroll
        for (int u = 0; u < 2; ++u)
            sc64[(size_t)bh * KK + kbase + u * 256 + tid] = a64[u] / (double)sqrtf(128.0f);
    } else {
#pragma unroll
        for (int q = 0; q < QQ; ++q) { lmq[q] = SENT; lzq[q] = 0.f; }
        if (tid < 16) {
            const float* krow = kn + ((size_t)bh * QQ + tid) * DHH;
            float acc[QQ];
#pragma unroll
            for (int q = 0; q < QQ; ++q) acc[q] = 0.f;
            for (int j = 0; j < DHH / 4; ++j) {
                float4 kv = ((const float4*)krow)[j];
#pragma unroll
                for (int q = 0; q < QQ; ++q) {
                    float4 qv = *(const float4*)(qs + q * DHH + j * 4);
                    acc[q] = fmaf(kv.x, qv.x, acc[q]);
                    acc[q] = fmaf(kv.y, qv.y, acc[q]);
                    acc[q] = fmaf(kv.z, qv.z, acc[q]);
                    acc[q] = fmaf(kv.w, qv.w, acc[q]);
                }
            }
            int key = PP + tid;
#pragma unroll
            for (int q = 0; q < QQ; ++q) {
                float sv = acc[q] / 11.313708498984761f;
                if (key > PP + q) sv += -1e9f;
                attn[((size_t)(bh * QQ + q)) * KK + key] = sv;
                lmq[q] = sv;
                lzq[q] = 1.f;
            }
            double a64 = 0.0;
            const double* kd = k64 + (size_t)(b * QQ + tid) * DD + h * DHH;
            for (int j = 0; j < DHH; ++j) a64 = fma(kd[j], q64s[j], a64);
            sc64[(size_t)bh * KK + key] = a64 / (double)sqrtf(128.0f);
        }
    }

    // cheap per-(row, chunk) partials: max butterfly (fmax only), single rescale
    // expf, add butterfly; one __syncthreads; 16-thread cross-wave combine.
    int wv = tid >> 6;
    int ln = tid & 63;
#pragma unroll 1
    for (int q = 0; q < QQ; ++q) {
        float lm = lmq[q];
        for (int off = 1; off < 64; off <<= 1)
            lm = fmaxf(lm, __shfl_xor(lm, off, 64));
        float z = lzq[q] * expf(lmq[q] - lm);
        for (int off = 1; off < 64; off <<= 1)
            z += __shfl_xor(z, off, 64);
        if (ln == 0) { swm[wv][q] = lm; swz[wv][q] = z; }
    }
    __syncthreads();
    if (tid < QQ) {
        int q = tid;
        float m0 = swm[0][q], m1 = swm[1][q], m2 = swm[2][q], m3 = swm[3][q];
        float m = fmaxf(fmaxf(m0, m1), fmaxf(m2, m3));
        float z = swz[0][q] * expf(m0 - m) + swz[1][q] * expf(m1 - m)
                + swz[2][q] * expf(m2 - m) + swz[3][q] * expf(m3 - m);
        pmax[(size_t)(bh * QQ + q) * 17 + ch] = m;
        psum[(size_t)(bh * QQ + q) * 17 + ch] = z;
    }
}

// ---------------------------------------------------------------- fused: stats combine (0-1) + rowstats64 (2-33)
__global__ __launch_bounds__(256) void fused_rowstats_kernel(
    const float* __restrict__ pmax, const float* __restrict__ psum,
    float* __restrict__ rowm, float* __restrict__ rowz,
    const double* __restrict__ sc, double* __restrict__ m64, double* __restrict__ z64)
{
    int bx = blockIdx.x, tid = threadIdx.x;
    __shared__ double dm[256], dz[256];
    if (bx < 2) {
        int row = bx * 256 + tid;
        float m = SENT, z = 0.f;
#pragma unroll
        for (int ch = 0; ch < 17; ++ch) {
            float pm = pmax[(size_t)row * 17 + ch];
            float pz = psum[(size_t)row * 17 + ch];
            float nm = fmaxf(m, pm);
            z = z * expf(m - nm) + pz * expf(pm - nm);
            m = nm;
        }
        rowm[row] = m;
        rowz[row] = z;
    } else {
        int row = bx - 2;
        const double* s = sc + (size_t)row * KK;
        double m = -INFINITY, z = 0.0;
        for (int k = tid; k < KK; k += 256) {
            double v = s[k];
            double nm = fmax(m, v);
            z = z * exp(m - nm) + exp(v - nm);
            m = nm;
        }
        dm[tid] = m; dz[tid] = z;
        __syncthreads();
        for (int off = 128; off > 0; off >>= 1) {
            if (tid < off) {
                double m1 = dm[tid], z1 = dz[tid];
                double m2 = dm[tid + off], z2 = dz[tid + off];
                double nm = fmax(m1, m2);
                dm[tid] = nm;
                dz[tid] = z1 * exp(m1 - nm) + z2 * exp(m2 - nm);
            }
            __syncthreads();
        }
        if (tid == 0) { m64[row] = dm[0]; z64[row] = dz[0]; }
    }
}

// ---------------------------------------------------------------- fused: PV (0-1055) + impkeys (1056-1088)
__global__ __launch_bounds__(256) void fused_pv_impkeys_kernel(
    float* __restrict__ attn, const float* __restrict__ past_v,
    const float* __restrict__ vn, const float* __restrict__ rowm,
    const float* __restrict__ rowz, float* __restrict__ part,
    const double* __restrict__ sc, const double* __restrict__ m64,
    const double* __restrict__ z64, unsigned long long* __restrict__ keys,
    int* __restrict__ rank)
{
    int bx = blockIdx.x, tid = threadIdx.x;
    __shared__ __align__(16) float p[QQ * 256];
    if (bx < 1056) {
        int bh = bx / 33, ch = bx - bh * 33;
        int nk = (ch < 32) ? 256 : 16;
        int kbase = ch * 256;
        if (tid < nk) {
            float sv[QQ];
#pragma unroll
            for (int q = 0; q < QQ; ++q)
                sv[q] = attn[((size_t)(bh * QQ + q)) * KK + kbase + tid];
#pragma unroll
            for (int q = 0; q < QQ; ++q) {
                int row = bh * QQ + q;
                float pv = expf(sv[q] - rowm[row]) / rowz[row];
                attn[((size_t)row) * KK + kbase + tid] = pv;
                p[q * 256 + tid] = pv;
            }
        }
        __syncthreads();

        int dq = tid & 31, q0 = tid >> 5;
        int d4 = dq * 4;
        float4 a0 = make_float4(0, 0, 0, 0), a1 = make_float4(0, 0, 0, 0);
        if (ch < 32) {
            const float* vbase = past_v + ((size_t)bh * PP + kbase) * DHH;
            for (int kk = 0; kk < 256; kk += 8) {
                float4 vb[8];
#pragma unroll
                for (int u = 0; u < 8; ++u)
                    vb[u] = *(const float4*)(vbase + (size_t)(kk + u) * DHH + d4);
#pragma unroll
                for (int u = 0; u < 8; ++u) {
                    float p0 = p[q0 * 256 + kk + u];
                    float p1 = p[(q0 + 8) * 256 + kk + u];
                    a0.x = fmaf(vb[u].x, p0, a0.x); a0.y = fmaf(vb[u].y, p0, a0.y);
                    a0.z = fmaf(vb[u].z, p0, a0.z); a0.w = fmaf(vb[u].w, p0, a0.w);
                    a1.x = fmaf(vb[u].x, p1, a1.x); a1.y = fmaf(vb[u].y, p1, a1.y);
                    a1.z = fmaf(vb[u].z, p1, a1.z); a1.w = fmaf(vb[u].w, p1, a1.w);
                }
            }
        } else {
            const float* vbase = vn + (size_t)bh * QQ * DHH;
            for (int kk = 0; kk < 16; ++kk) {
                float4 v4 = *(const float4*)(vbase + (size_t)kk * DHH + d4);
                float p0 = p[q0 * 256 + kk];
                float p1 = p[(q0 + 8) * 256 + kk];
                a0.x = fmaf(v4.x, p0, a0.x); a0.y = fmaf(v4.y, p0, a0.y);
                a0.z = fmaf(v4.z, p0, a0.z); a0.w = fmaf(v4.w, p0, a0.w);
                a1.x = fmaf(v4.x, p1, a1.x); a1.y = fmaf(v4.y, p1, a1.y);
                a1.z = fmaf(v4.z, p1, a1.z); a1.w = fmaf(v4.w, p1, a1.w);
            }
        }
        size_t pb = ((size_t)ch * BH + bh) * (QQ * DHH);
        *(float4*)(part + pb + q0 * DHH + d4) = a0;
        *(float4*)(part + pb + (q0 + 8) * DHH + d4) = a1;
    } else {
        int k = (bx - 1056) * 256 + tid;
        if (k >= KK) return;
        rank[k] = 0;
        double t = 0.0;
        for (int bh = 0; bh < BH; ++bh)
            t += exp(sc[(size_t)bh * KK + k] - m64[bh]) / z64[bh];
        double imp = t / 32.0;
        if (k == KK - 1) imp = INFINITY;
        unsigned long long bits = (unsigned long long)__double_as_longlong(imp);
        keys[k] = (bits & ~0x3FFFull) | (unsigned long long)k;
    }
}

// ---------------------------------------------------------------- fused: PV reduce (0-255) + rankpart (256-519)
__global__ __launch_bounds__(256) void fused_pvred_rankpart_kernel(
    const float* __restrict__ part, float* __restrict__ oattn,
    const unsigned long long* __restrict__ keys, int* __restrict__ rank)
{
    int bx = blockIdx.x, tid = threadIdx.x;
    __shared__ unsigned long long chnk[1026];
    if (bx < 256) {
        int e = bx * 256 + tid;
        float sa = 0.f, sb = 0.f;
#pragma unroll 8
        for (int ch = 0; ch < 16; ++ch) sa += part[(size_t)ch * 65536 + e];
#pragma unroll 8
        for (int ch = 16; ch < 33; ++ch) sb += part[(size_t)ch * 65536 + e];
        float s = sa + sb;
        int bh = e >> 11, rem = e & 2047, q = rem >> 7, d = rem & 127;
        int b = bh >> 4, h = bh & 15;
        oattn[((size_t)(b * QQ + q)) * DD + h * DHH + d] = s;
    } else {
        int idx = bx - 256;
        int xb = idx % 33, yb = idx / 33;
        int gid = xb * 256 + tid;
        int base = yb * 1026;
        for (int i = tid; i < 1026; i += 256) chnk[i] = keys[base + i];
        __syncthreads();
        if (gid >= KK) return;
        unsigned long long mykey = keys[gid];
        int cnt = 0;
#pragma unroll 6
        for (int i = 0; i < 1026; ++i) cnt += (chnk[i] < mykey) ? 1 : 0;
        atomicAdd(&rank[gid], cnt);
    }
}

// ---------------------------------------------------------------- fused: Wo GEMM (0-255) + rankwrite (256-288)
__global__ __launch_bounds__(256) void fused_wogemm_rankwrite_kernel(
    const float* __restrict__ A, const float* __restrict__ wo,
    float* __restrict__ part,
    const unsigned long long* __restrict__ keys, const int* __restrict__ rank,
    float* __restrict__ outp)
{
    int bx = blockIdx.x, tid = threadIdx.x;
    __shared__ __align__(16) float xs[32 * 32];
    if (bx < 256) {
        int cc = bx & 3, kc = bx >> 2;
        int col0 = cc * 512 + tid;
        int d0 = kc * 32;
        for (int i = tid; i < 32 * 32; i += 256) {
            int r = i >> 5, d = i & 31;
            xs[i] = A[(size_t)r * DD + d0 + d];
        }
        __syncthreads();
        float acc0[32], acc1[32];
#pragma unroll
        for (int r = 0; r < 32; ++r) { acc0[r] = 0.f; acc1[r] = 0.f; }
        const float* wp = wo + (size_t)d0 * DD + col0;
        for (int d = 0; d < 32; d += 8) {
            float wb0[8], wb1[8];
#pragma unroll
            for (int u = 0; u < 8; ++u) {
                wb0[u] = wp[(size_t)(d + u) * DD];
                wb1[u] = wp[(size_t)(d + u) * DD + 256];
            }
#pragma unroll
            for (int r = 0; r < 32; ++r) {
                const float4 x0 = *(const float4*)(xs + r * 32 + d);
                const float4 x1 = *(const float4*)(xs + r * 32 + d + 4);
                float a = acc0[r], b = acc1[r];
                a = fmaf(x0.x, wb0[0], a);  b = fmaf(x0.x, wb1[0], b);
                a = fmaf(x0.y, wb0[1], a);  b = fmaf(x0.y, wb1[1], b);
                a = fmaf(x0.z, wb0[2], a);  b = fmaf(x0.z, wb1[2], b);
                a = fmaf(x0.w, wb0[3], a);  b = fmaf(x0.w, wb1[3], b);
                a = fmaf(x1.x, wb0[4], a);  b = fmaf(x1.x, wb1[4], b);
                a = fmaf(x1.y, wb0[5], a);  b = fmaf(x1.y, wb1[5], b);
                a = fmaf(x1.z, wb0[6], a);  b = fmaf(x1.z, wb1[6], b);
                a = fmaf(x1.w, wb0[7], a);  b = fmaf(x1.w, wb1[7], b);
                acc0[r] = a; acc1[r] = b;
            }
        }
#pragma unroll
        for (int r = 0; r < 32; ++r) {
            part[((size_t)(kc * 32 + r)) * DD + col0] = acc0[r];
            part[((size_t)(kc * 32 + r)) * DD + col0 + 256] = acc1[r];
        }
    } else {
        int gid = (bx - 256) * 256 + tid;
        if (gid >= KK) return;
        int r = rank[gid];
        if (r < NPRUNE)
            outp[r] = (float)(unsigned)(keys[gid] & 0x3FFFu);
    }
}

// ---------------------------------------------------------------- Wo reduce + residual (dual 32+32)
__global__ __launch_bounds__(256) void reduce_wo_kernel(
    const float* __restrict__ part, const float* __restrict__ resid,
    float* __restrict__ hbuf)
{
    int e = blockIdx.x * 256 + threadIdx.x;
    float sa = 0.f, sb = 0.f;
#pragma unroll 8
    for (int kc = 0; kc < 32; ++kc) {
        sa += part[(size_t)kc * 65536 + e];
        sb += part[(size_t)(kc + 32) * 65536 + e];
    }
    hbuf[e] = resid[e] + (sa + sb);
}

// ---------------------------------------------------------------- fused gate+up reduce + silu
__global__ __launch_bounds__(256) void reduce_gateup_silu_kernel(
    const float* __restrict__ part, float* __restrict__ act)
{
    int e = blockIdx.x * 256 + threadIdx.x;
    float ga = 0.f, gb = 0.f, ua = 0.f, ub = 0.f;
#pragma unroll 8
    for (int kc = 0; kc < 16; ++kc) {
        ga += part[(size_t)kc * 180224 + e];
        gb += part[(size_t)(kc + 16) * 180224 + e];
        ua += part[(size_t)(kc + 32) * 180224 + e];
        ub += part[(size_t)(kc + 48) * 180224 + e];
    }
    float g = ga + gb, u = ua + ub;
    float sg = g / (1.f + expf(-g));
    act[e] = sg * u;
}

// ---------------------------------------------------------------- down reduce + residual (dual 88+88)
__global__ __launch_bounds__(256) void reduce_down_kernel(
    const float* __restrict__ part, const float* __restrict__ hbuf,
    float* __restrict__ out)
{
    int e = blockIdx.x * 256 + threadIdx.x;
    float sa = 0.f, sb = 0.f;
#pragma unroll 8
    for (int kc = 0; kc < 88; ++kc) {
        sa += part[(size_t)kc * 65536 + e];
        sb += part[(size_t)(kc + 88) * 65536 + e];
    }
    out[e] = hbuf[e] + (sa + sb);
}

// ================================================================ launch
extern "C" void kernel_launch(void* const* d_in, const int* in_sizes, int n_in,
                              void* d_out, int out_size, void* d_ws, size_t ws_size,
                              hipStream_t stream)
{
    const float* hidden = (const float*)d_in[0];
    const float* past_k = (const float*)d_in[1];
    const float* past_v = (const float*)d_in[2];
    const float* wq     = (const float*)d_in[3];
    const float* wk     = (const float*)d_in[4];
    const float* wv     = (const float*)d_in[5];
    const float* wo     = (const float*)d_in[6];
    const float* wgate  = (const float*)d_in[7];
    const float* wup    = (const float*)d_in[8];
    const float* wdown  = (const float*)d_in[9];
    const float* n1w    = (const float*)d_in[10];
    const float* n2w    = (const float*)d_in[11];

    float* out_hidden = (float*)d_out;
    float* attn = out_hidden + (size_t)RR * DD;
    float* out_prune = attn + (size_t)BH * QQ * KK;
    float* ws = (float*)d_ws;
    double* p64part = (double*)(ws + OFF_P64P);
    double* f64 = (double*)(ws + OFF_F64);
    double* x64 = f64 + D_X64;
    double* k64 = f64 + D_K64;
    double* q64 = f64 + D_Q64;
    double* m64 = f64 + D_M64;
    double* z64 = f64 + D_Z64;
    double* sc64 = f64 + D_SC;
    unsigned long long* keys = (unsigned long long*)(f64 + D_KEYS);
    int* rank = (int*)(ws + OFF_RANK);
    float* pmax = ws + OFF_PMAX;
    float* psum = ws + OFF_PSUM;

    // 1. rmsnorm1 + rms32mix
    fused_rms_kernel<<<dim3(64), dim3(256), 0, stream>>>(hidden, n1w, ws + OFF_X, x64);

    // 2. QKV GEMM + proj64_part
    fused_qkv_p64_kernel<<<dim3(1024), dim3(256), 0, stream>>>(
        ws + OFF_X, wq, wk, wv, ws + OFF_UNION, x64, p64part);

    // 3. QKV reduce+RoPE + proj64 reduce+RoPE
    fused_reduce_kernel<<<dim3(528), dim3(256), 0, stream>>>(
        ws + OFF_UNION, ws + OFF_QR, ws + OFF_KN, ws + OFF_VN, p64part, k64, q64);

    // 4. scores (+ f64 + cheap softmax partials)
    scores_kernel<<<dim3(BH, 17), dim3(256), 0, stream>>>(
        ws + OFF_QR, past_k, ws + OFF_KN, attn, q64, k64, sc64, pmax, psum);

    // 5. stats combine (2) + rowstats64 (32)
    fused_rowstats_kernel<<<dim3(34), dim3(256), 0, stream>>>(
        pmax, psum, ws + OFF_ROWM, ws + OFF_ROWZ, sc64, m64, z64);

    // 6. PV + impkeys
    fused_pv_impkeys_kernel<<<dim3(1089), dim3(256), 0, stream>>>(
        attn, past_v, ws + OFF_VN, ws + OFF_ROWM, ws + OFF_ROWZ, ws + OFF_UNION,
        sc64, m64, z64, keys, rank);

    // 7. PV reduce + rankpart
    fused_pvred_rankpart_kernel<<<dim3(520), dim3(256), 0, stream>>>(
        ws + OFF_UNION, ws + OFF_OATTN, keys, rank);

    // 8. Wo GEMM + rankwrite
    fused_wogemm_rankwrite_kernel<<<dim3(289), dim3(256), 0, stream>>>(
        ws + OFF_OATTN, wo, ws + OFF_UNION, keys, rank, out_prune);

    // 9. + residual
    reduce_wo_kernel<<<dim3(256), dim3(256), 0, stream>>>(ws + OFF_UNION, hidden, ws + OFF_H);

    // 10. rmsnorm2
    rmsnorm_kernel<<<dim3(RR), dim3(256), 0, stream>>>(ws + OFF_H, n2w, ws + OFF_Y);

    // 11. gate+up GEMM + fused reduce+silu
    gemm32c2<64><<<dim3(11, 32, 2), dim3(256), 0, stream>>>(
        ws + OFF_Y, wgate, wup, wup, ws + OFF_UNION, DD, FF, (size_t)32 * 180224);
    reduce_gateup_silu_kernel<<<dim3(704), dim3(256), 0, stream>>>(
        ws + OFF_UNION, ws + OFF_ACT);

    // 12. down GEMM + reduce
    gemm32c2<32><<<dim3(4, 176, 1), dim3(256), 0, stream>>>(
        ws + OFF_ACT, wdown, wdown, wdown, ws + OFF_UNION, FF, DD, 0);
    reduce_down_kernel<<<dim3(256), dim3(256), 0, stream>>>(
        ws + OFF_UNION, ws + OFF_H, out_hidden);
}

// Round 20
// 324.781 us; speedup vs baseline: 1.0611x; 1.0146x over previous
//
#include <hip/hip_runtime.h>
#include <math.h>

// Problem constants
#define BB 2
#define QQ 16
#define DD 2048
#define HH 16
#define DHH 128
#define PP 8192
#define FF 5632
#define KK 8208
#define BH 32
#define RR 32      // B*Q rows
#define NPRUNE 820

// Workspace layout (float offsets). ws_size ~512 MiB.
#define OFF_X      0u
#define OFF_QR     65536u
#define OFF_KN     131072u
#define OFF_VN     196608u
#define OFF_ROWM   262144u
#define OFF_ROWZ   262656u
#define OFF_OATTN  263168u
#define OFF_H      328704u
#define OFF_Y      394240u
#define OFF_ACT    459776u
#define OFF_UNION  640064u      // partial region, reused sequentially (r17 audit)
#define OFF_P64P   (OFF_UNION + 12582912u)  // proj64 partials, 4456448 floats
#define OFF_F64    (OFF_P64P + 4456448u)
#define D_X64      0u
#define D_K64      65536u
#define D_Q64      131072u
#define D_M64      135168u
#define D_Z64      135200u
#define D_SC       135232u
#define D_KEYS     397888u
#define OFF_RANK   (OFF_F64 + 812192u)      // 8208 ints

// ---------------------------------------------------------------- rmsnorm (f32, norm2)
__global__ __launch_bounds__(256) void rmsnorm_kernel(
    const float* __restrict__ in, const float* __restrict__ w,
    float* __restrict__ out)
{
    int r = blockIdx.x;
    const float* x = in + (size_t)r * DD;
    float ss = 0.f;
    for (int c = threadIdx.x; c < DD; c += 256) { float v = x[c]; ss = fmaf(v, v, ss); }
    __shared__ float red[256];
    red[threadIdx.x] = ss;
    __syncthreads();
    for (int off = 128; off > 0; off >>= 1) {
        if (threadIdx.x < off) red[threadIdx.x] += red[threadIdx.x + off];
        __syncthreads();
    }
    float mean = red[0] / (float)DD;
    float scale = 1.0f / sqrtf(mean + 1e-5f);
    for (int c = threadIdx.x; c < DD; c += 256)
        out[(size_t)r * DD + c] = x[c] * scale * w[c];
}

// ---------------------------------------------------------------- fused: rmsnorm1 (0-31) + rms32mix (32-63)
__global__ __launch_bounds__(256) void fused_rms_kernel(
    const float* __restrict__ in, const float* __restrict__ w,
    float* __restrict__ out32, double* __restrict__ out64)
{
    int bx = blockIdx.x, tid = threadIdx.x;
    __shared__ float red[256];
    __shared__ float bs[16];
    __shared__ float sscale;
    if (bx < 32) {
        int r = bx;
        const float* x = in + (size_t)r * DD;
        float ss = 0.f;
        for (int c = tid; c < DD; c += 256) { float v = x[c]; ss = fmaf(v, v, ss); }
        red[tid] = ss;
        __syncthreads();
        for (int off = 128; off > 0; off >>= 1) {
            if (tid < off) red[tid] += red[tid + off];
            __syncthreads();
        }
        float mean = red[0] / (float)DD;
        float scale = 1.0f / sqrtf(mean + 1e-5f);
        for (int c = tid; c < DD; c += 256)
            out32[(size_t)r * DD + c] = x[c] * scale * w[c];
    } else {
        int r = bx - 32;
        const float* x = in + (size_t)r * DD;
        if (tid < 16) {
            const float* a = x + tid * 128;
            float rr[8];
#pragma unroll
            for (int j = 0; j < 8; ++j) { float v = a[j]; rr[j] = __fmul_rn(v, v); }
            for (int i = 8; i < 128; i += 8) {
#pragma unroll
                for (int j = 0; j < 8; ++j) {
                    float v = a[i + j];
                    rr[j] = __fadd_rn(rr[j], __fmul_rn(v, v));
                }
            }
            float t01 = __fadd_rn(rr[0], rr[1]);
            float t23 = __fadd_rn(rr[2], rr[3]);
            float t45 = __fadd_rn(rr[4], rr[5]);
            float t67 = __fadd_rn(rr[6], rr[7]);
            bs[tid] = __fadd_rn(__fadd_rn(t01, t23), __fadd_rn(t45, t67));
        }
        __syncthreads();
        if (tid == 0) {
            float c[8], d[4], e[2];
#pragma unroll
            for (int i = 0; i < 8; ++i) c[i] = __fadd_rn(bs[2 * i], bs[2 * i + 1]);
#pragma unroll
            for (int i = 0; i < 4; ++i) d[i] = __fadd_rn(c[2 * i], c[2 * i + 1]);
            e[0] = __fadd_rn(d[0], d[1]);
            e[1] = __fadd_rn(d[2], d[3]);
            float s = __fadd_rn(e[0], e[1]);
            float v = __fdiv_rn(s, 2048.0f);
            float ve = __fadd_rn(v, 1e-5f);
            float sq = __fsqrt_rn(ve);
            sscale = __fdiv_rn(1.0f, sq);
        }
        __syncthreads();
        double scd = (double)sscale;
        for (int c = tid; c < DD; c += 256)
            out64[(size_t)r * DD + c] = ((double)x[c] * scd) * (double)w[c];
    }
}

// ---------------------------------------------------------------- 32-row GEMM, 2 cols/thread
template<int DCHUNK>
__global__ __launch_bounds__(256) void gemm32c2(
    const float* __restrict__ A, const float* __restrict__ w0,
    const float* __restrict__ w1, const float* __restrict__ w2,
    float* __restrict__ part, int Kdim, int N, size_t zstride)
{
    int cc = blockIdx.x, kc = blockIdx.y, z = blockIdx.z;
    int tid = threadIdx.x;
    int col0 = cc * 512 + tid;
    int d0 = kc * DCHUNK;
    const float* W = (z == 0) ? w0 : (z == 1) ? w1 : w2;
    __shared__ __align__(16) float xs[32 * DCHUNK];
    for (int i = tid; i < 32 * DCHUNK; i += 256) {
        int r = i / DCHUNK, d = i - r * DCHUNK;
        xs[i] = A[(size_t)r * Kdim + d0 + d];
    }
    __syncthreads();
    float acc0[32], acc1[32];
#pragma unroll
    for (int r = 0; r < 32; ++r) { acc0[r] = 0.f; acc1[r] = 0.f; }
    const float* wp = W + (size_t)d0 * N + col0;
    for (int d = 0; d < DCHUNK; d += 8) {
        float wb0[8], wb1[8];
#pragma unroll
        for (int u = 0; u < 8; ++u) {
            wb0[u] = wp[(size_t)(d + u) * N];
            wb1[u] = wp[(size_t)(d + u) * N + 256];
        }
#pragma unroll
        for (int r = 0; r < 32; ++r) {
            const float4 x0 = *(const float4*)(xs + r * DCHUNK + d);
            const float4 x1 = *(const float4*)(xs + r * DCHUNK + d + 4);
            float a = acc0[r], b = acc1[r];
            a = fmaf(x0.x, wb0[0], a);  b = fmaf(x0.x, wb1[0], b);
            a = fmaf(x0.y, wb0[1], a);  b = fmaf(x0.y, wb1[1], b);
            a = fmaf(x0.z, wb0[2], a);  b = fmaf(x0.z, wb1[2], b);
            a = fmaf(x0.w, wb0[3], a);  b = fmaf(x0.w, wb1[3], b);
            a = fmaf(x1.x, wb0[4], a);  b = fmaf(x1.x, wb1[4], b);
            a = fmaf(x1.y, wb0[5], a);  b = fmaf(x1.y, wb1[5], b);
            a = fmaf(x1.z, wb0[6], a);  b = fmaf(x1.z, wb1[6], b);
            a = fmaf(x1.w, wb0[7], a);  b = fmaf(x1.w, wb1[7], b);
            acc0[r] = a; acc1[r] = b;
        }
    }
    float* dst = part + (size_t)z * zstride;
#pragma unroll
    for (int r = 0; r < 32; ++r) {
        dst[((size_t)(kc * 32 + r)) * N + col0] = acc0[r];
        dst[((size_t)(kc * 32 + r)) * N + col0 + 256] = acc1[r];
    }
}

// ---------------------------------------------------------------- fused: QKV GEMM (0-767) + proj64_part (768-1023)
__global__ __launch_bounds__(256) void fused_qkv_p64_kernel(
    const float* __restrict__ A, const float* __restrict__ wq,
    const float* __restrict__ wk, const float* __restrict__ wv,
    float* __restrict__ part, const double* __restrict__ x64,
    double* __restrict__ p64)
{
    int bx = blockIdx.x, tid = threadIdx.x;
    __shared__ __align__(16) float xs[32 * 32];
    __shared__ double xs64[34 * 64];
    if (bx < 768) {
        int cc = bx & 3, kc = (bx >> 2) & 63, z = bx >> 8;
        int col0 = cc * 512 + tid;
        int d0 = kc * 32;
        const float* W = (z == 0) ? wq : (z == 1) ? wk : wv;
        for (int i = tid; i < 32 * 32; i += 256) {
            int r = i >> 5, d = i & 31;
            xs[i] = A[(size_t)r * DD + d0 + d];
        }
        __syncthreads();
        float acc0[32], acc1[32];
#pragma unroll
        for (int r = 0; r < 32; ++r) { acc0[r] = 0.f; acc1[r] = 0.f; }
        const float* wp = W + (size_t)d0 * DD + col0;
        for (int d = 0; d < 32; d += 8) {
            float wb0[8], wb1[8];
#pragma unroll
            for (int u = 0; u < 8; ++u) {
                wb0[u] = wp[(size_t)(d + u) * DD];
                wb1[u] = wp[(size_t)(d + u) * DD + 256];
            }
#pragma unroll
            for (int r = 0; r < 32; ++r) {
                const float4 x0 = *(const float4*)(xs + r * 32 + d);
                const float4 x1 = *(const float4*)(xs + r * 32 + d + 4);
                float a = acc0[r], b = acc1[r];
                a = fmaf(x0.x, wb0[0], a);  b = fmaf(x0.x, wb1[0], b);
                a = fmaf(x0.y, wb0[1], a);  b = fmaf(x0.y, wb1[1], b);
                a = fmaf(x0.z, wb0[2], a);  b = fmaf(x0.z, wb1[2], b);
                a = fmaf(x0.w, wb0[3], a);  b = fmaf(x0.w, wb1[3], b);
                a = fmaf(x1.x, wb0[4], a);  b = fmaf(x1.x, wb1[4], b);
                a = fmaf(x1.y, wb0[5], a);  b = fmaf(x1.y, wb1[5], b);
                a = fmaf(x1.z, wb0[6], a);  b = fmaf(x1.z, wb1[6], b);
                a = fmaf(x1.w, wb0[7], a);  b = fmaf(x1.w, wb1[7], b);
                acc0[r] = a; acc1[r] = b;
            }
        }
        float* dst = part + (size_t)z * 64 * 65536;
#pragma unroll
        for (int r = 0; r < 32; ++r) {
            dst[((size_t)(kc * 32 + r)) * DD + col0] = acc0[r];
            dst[((size_t)(kc * 32 + r)) * DD + col0 + 256] = acc1[r];
        }
    } else {
        int p = bx - 768;
        int cc = p & 7, kc = p >> 3;
        int col = cc * 256 + tid;
        int d0 = kc * 64;
        for (int i = tid; i < 34 * 64; i += 256) {
            int r = i >> 6, d = i & 63;
            int srcrow = (r < 32) ? r : ((r == 32) ? 15 : 31);
            xs64[i] = x64[(size_t)srcrow * DD + d0 + d];
        }
        __syncthreads();
        double acc[34];
#pragma unroll
        for (int r = 0; r < 34; ++r) acc[r] = 0.0;
        const float* wkp = wk + (size_t)d0 * DD + col;
        const float* wqp = wq + (size_t)d0 * DD + col;
        for (int d = 0; d < 64; d += 4) {
            double wkb[4], wqb[4];
#pragma unroll
            for (int u = 0; u < 4; ++u) {
                wkb[u] = (double)wkp[(size_t)(d + u) * DD];
                wqb[u] = (double)wqp[(size_t)(d + u) * DD];
            }
#pragma unroll
            for (int u = 0; u < 4; ++u) {
#pragma unroll
                for (int r = 0; r < 32; ++r) acc[r] = fma(xs64[r * 64 + d + u], wkb[u], acc[r]);
                acc[32] = fma(xs64[32 * 64 + d + u], wqb[u], acc[32]);
                acc[33] = fma(xs64[33 * 64 + d + u], wqb[u], acc[33]);
            }
        }
#pragma unroll
        for (int r = 0; r < 34; ++r)
            p64[((size_t)kc * 34 + r) * DD + col] = acc[r];
    }
}

// ---------------------------------------------------------------- fused: QKV reduce+RoPE (0-255) + proj64 reduce+RoPE (256-527)
__global__ __launch_bounds__(256) void fused_reduce_kernel(
    const float* __restrict__ part, float* __restrict__ qr,
    float* __restrict__ kn, float* __restrict__ vn,
    const double* __restrict__ p64, double* __restrict__ k64,
    double* __restrict__ q64)
{
    int bx = blockIdx.x, tid = threadIdx.x;
    __shared__ float buf[256];
    __shared__ double dbuf[256];
    if (bx < 256) {
        int r = bx >> 3;
        int b = r >> 4, qi = r & 15;
        int c = (bx & 7) * 256 + tid;
        int h = c >> 7, dh = c & 127, j = dh & 63;
        float invf = (float)exp(-((double)j / 64.0) * log(10000.0));
        float ang = (float)(PP + qi) * invf;
        float sn, cs;
        sincosf(ang, &sn, &cs);
        size_t dsti = (((size_t)(b * HH + h)) * QQ + qi) * DHH + dh;
        for (int mat = 0; mat < 3; ++mat) {
            const float* pm = part + (size_t)mat * 64 * 65536 + (size_t)r * DD + c;
            float sa = 0.f, sb = 0.f;
#pragma unroll 8
            for (int kc = 0; kc < 32; ++kc) {
                sa += pm[(size_t)kc * 32 * DD];
                sb += pm[(size_t)(kc + 32) * 32 * DD];
            }
            float s = sa + sb;
            buf[tid] = s;
            __syncthreads();
            float val;
            if (mat == 2) {
                val = s;
            } else {
                float other = (dh < 64) ? -buf[tid + 64] : buf[tid - 64];
                val = s * cs + other * sn;
            }
            float* dst = (mat == 0) ? qr : (mat == 1) ? kn : vn;
            dst[dsti] = val;
            __syncthreads();
        }
    } else {
        int e = (bx - 256) * 256 + tid;
        int r = e >> 11, col = e & 2047;
        double s = 0.0;
#pragma unroll 8
        for (int kc = 0; kc < 32; ++kc) s += p64[((size_t)kc * 34 + r) * DD + col];
        dbuf[tid] = s;
        __syncthreads();
        int dh = col & 127, j = dh & 63;
        int pos = (r < 32) ? (PP + (r & 15)) : (PP + 15);
        float pf = (float)pow(10000.0, (double)j / 64.0);
        float invf = __fdiv_rn(1.0f, pf);
        float ang = __fmul_rn((float)pos, invf);
        float cs = (float)cos((double)ang);
        float sn = (float)sin((double)ang);
        double outv;
        if (dh < 64) outv = s * (double)cs - dbuf[tid + 64] * (double)sn;
        else         outv = s * (double)cs + dbuf[tid - 64] * (double)sn;
        if (r < 32) k64[(size_t)r * DD + col] = outv;
        else        q64[(size_t)(r - 32) * DD + col] = outv;
    }
}

// ---------------------------------------------------------------- scores + f64 (K read once)
__global__ __launch_bounds__(256) void scores_kernel(
    const float* __restrict__ qr, const float* __restrict__ past_k,
    const float* __restrict__ kn, float* __restrict__ attn,
    const double* __restrict__ q64, const double* __restrict__ k64,
    double* __restrict__ sc64)
{
    int bh = blockIdx.x, ch = blockIdx.y;
    int b = bh >> 4, h = bh & 15;
    int tid = threadIdx.x;
    __shared__ __align__(16) float qs[QQ * DHH];
    __shared__ double q64s[DHH];
    for (int i = tid; i < QQ * DHH; i += 256) qs[i] = qr[(size_t)bh * (QQ * DHH) + i];
    if (tid < DHH) q64s[tid] = q64[(size_t)b * DD + h * DHH + tid];
    __syncthreads();

    if (ch < 16) {
        int kbase = ch * 512;
        const float* kr0 = past_k + ((size_t)bh * PP + kbase + tid) * DHH;
        float acc[2][QQ];
#pragma unroll
        for (int u = 0; u < 2; ++u)
#pragma unroll
            for (int q = 0; q < QQ; ++q) acc[u][q] = 0.f;
        double a64[2] = {0.0, 0.0};

        for (int jb = 0; jb < DHH / 4; jb += 2) {
            float4 kb[2][2];
#pragma unroll
            for (int u = 0; u < 2; ++u) {
                const float4* kp = (const float4*)(kr0 + (size_t)u * 256 * DHH);
                kb[u][0] = kp[jb];
                kb[u][1] = kp[jb + 1];
            }
#pragma unroll
            for (int jj = 0; jj < 2; ++jj) {
#pragma unroll
                for (int q = 0; q < QQ; ++q) {
                    float4 qv = *(const float4*)(qs + q * DHH + (jb + jj) * 4);
#pragma unroll
                    for (int u = 0; u < 2; ++u) {
                        acc[u][q] = fmaf(kb[u][jj].x, qv.x, acc[u][q]);
                        acc[u][q] = fmaf(kb[u][jj].y, qv.y, acc[u][q]);
                        acc[u][q] = fmaf(kb[u][jj].z, qv.z, acc[u][q]);
                        acc[u][q] = fmaf(kb[u][jj].w, qv.w, acc[u][q]);
                    }
                }
            }
#pragma unroll
            for (int jj = 0; jj < 2; ++jj) {
                int j = jb + jj;
#pragma unroll
                for (int u = 0; u < 2; ++u) {
                    a64[u] = fma((double)kb[u][jj].x, q64s[j * 4 + 0], a64[u]);
                    a64[u] = fma((double)kb[u][jj].y, q64s[j * 4 + 1], a64[u]);
                    a64[u] = fma((double)kb[u][jj].z, q64s[j * 4 + 2], a64[u]);
                    a64[u] = fma((double)kb[u][jj].w, q64s[j * 4 + 3], a64[u]);
                }
            }
        }
#pragma unroll
        for (int q = 0; q < QQ; ++q) {
#pragma unroll
            for (int u = 0; u < 2; ++u) {
                int key = kbase + u * 256 + tid;
                float sv = acc[u][q] / 11.313708498984761f;
                if (key > PP + q) sv += -1e9f;
                attn[((size_t)(bh * QQ + q)) * KK + key] = sv;
            }
        }
#pragma unroll
        for (int u = 0; u < 2; ++u)
            sc64[(size_t)bh * KK + kbase + u * 256 + tid] = a64[u] / (double)sqrtf(128.0f);
    } else {
        if (tid >= 16) return;
        const float* krow = kn + ((size_t)bh * QQ + tid) * DHH;
        float acc[QQ];
#pragma unroll
        for (int q = 0; q < QQ; ++q) acc[q] = 0.f;
        for (int j = 0; j < DHH / 4; ++j) {
            float4 kv = ((const float4*)krow)[j];
#pragma unroll
            for (int q = 0; q < QQ; ++q) {
                float4 qv = *(const float4*)(qs + q * DHH + j * 4);
                acc[q] = fmaf(kv.x, qv.x, acc[q]);
                acc[q] = fmaf(kv.y, qv.y, acc[q]);
                acc[q] = fmaf(kv.z, qv.z, acc[q]);
                acc[q] = fmaf(kv.w, qv.w, acc[q]);
            }
        }
        int key = PP + tid;
#pragma unroll
        for (int q = 0; q < QQ; ++q) {
            float sv = acc[q] / 11.313708498984761f;
            if (key > PP + q) sv += -1e9f;
            attn[((size_t)(bh * QQ + q)) * KK + key] = sv;
        }
        double a64 = 0.0;
        const double* kd = k64 + (size_t)(b * QQ + tid) * DD + h * DHH;
        for (int j = 0; j < DHH; ++j) a64 = fma(kd[j], q64s[j], a64);
        sc64[(size_t)bh * KK + key] = a64 / (double)sqrtf(128.0f);
    }
}

// ---------------------------------------------------------------- fused: rowstats f32 (0-511) + rowstats f64 (512-543)
__global__ __launch_bounds__(256) void fused_rowstats_kernel(
    const float* __restrict__ attn, float* __restrict__ rowm, float* __restrict__ rowz,
    const double* __restrict__ sc, double* __restrict__ m64, double* __restrict__ z64)
{
    int bx = blockIdx.x, tid = threadIdx.x;
    __shared__ float sm[256], sz[256];
    __shared__ double dm[256], dz[256];
    if (bx < 512) {
        int row = bx;
        const float* s = attn + (size_t)row * KK;
        float m = -INFINITY, z = 0.f;
        for (int k = tid; k < KK; k += 256) {
            float v = s[k];
            float nm = fmaxf(m, v);
            z = z * expf(m - nm) + expf(v - nm);
            m = nm;
        }
        sm[tid] = m; sz[tid] = z;
        __syncthreads();
        for (int off = 128; off > 0; off >>= 1) {
            if (tid < off) {
                float m1 = sm[tid], z1 = sz[tid];
                float m2 = sm[tid + off], z2 = sz[tid + off];
                float nm = fmaxf(m1, m2);
                sm[tid] = nm;
                sz[tid] = z1 * expf(m1 - nm) + z2 * expf(m2 - nm);
            }
            __syncthreads();
        }
        if (tid == 0) { rowm[row] = sm[0]; rowz[row] = sz[0]; }
    } else {
        int row = bx - 512;
        const double* s = sc + (size_t)row * KK;
        double m = -INFINITY, z = 0.0;
        for (int k = tid; k < KK; k += 256) {
            double v = s[k];
            double nm = fmax(m, v);
            z = z * exp(m - nm) + exp(v - nm);
            m = nm;
        }
        dm[tid] = m; dz[tid] = z;
        __syncthreads();
        for (int off = 128; off > 0; off >>= 1) {
            if (tid < off) {
                double m1 = dm[tid], z1 = dz[tid];
                double m2 = dm[tid + off], z2 = dz[tid + off];
                double nm = fmax(m1, m2);
                dm[tid] = nm;
                dz[tid] = z1 * exp(m1 - nm) + z2 * exp(m2 - nm);
            }
            __syncthreads();
        }
        if (tid == 0) { m64[row] = dm[0]; z64[row] = dz[0]; }
    }
}

// ---------------------------------------------------------------- fused: PV (0-1055) + impkeys (1056-1088)
__global__ __launch_bounds__(256) void fused_pv_impkeys_kernel(
    float* __restrict__ attn, const float* __restrict__ past_v,
    const float* __restrict__ vn, const float* __restrict__ rowm,
    const float* __restrict__ rowz, float* __restrict__ part,
    const double* __restrict__ sc, const double* __restrict__ m64,
    const double* __restrict__ z64, unsigned long long* __restrict__ keys,
    int* __restrict__ rank)
{
    int bx = blockIdx.x, tid = threadIdx.x;
    __shared__ __align__(16) float p[QQ * 256];
    if (bx < 1056) {
        int bh = bx / 33, ch = bx - bh * 33;
        int nk = (ch < 32) ? 256 : 16;
        int kbase = ch * 256;
        if (tid < nk) {
            float sv[QQ];
#pragma unroll
            for (int q = 0; q < QQ; ++q)
                sv[q] = attn[((size_t)(bh * QQ + q)) * KK + kbase + tid];
#pragma unroll
            for (int q = 0; q < QQ; ++q) {
                int row = bh * QQ + q;
                float pv = expf(sv[q] - rowm[row]) / rowz[row];
                attn[((size_t)row) * KK + kbase + tid] = pv;
                p[q * 256 + tid] = pv;
            }
        }
        __syncthreads();

        int dq = tid & 31, q0 = tid >> 5;
        int d4 = dq * 4;
        float4 a0 = make_float4(0, 0, 0, 0), a1 = make_float4(0, 0, 0, 0);
        if (ch < 32) {
            const float* vbase = past_v + ((size_t)bh * PP + kbase) * DHH;
            for (int kk = 0; kk < 256; kk += 8) {
                float4 vb[8];
#pragma unroll
                for (int u = 0; u < 8; ++u)
                    vb[u] = *(const float4*)(vbase + (size_t)(kk + u) * DHH + d4);
#pragma unroll
                for (int u = 0; u < 8; ++u) {
                    float p0 = p[q0 * 256 + kk + u];
                    float p1 = p[(q0 + 8) * 256 + kk + u];
                    a0.x = fmaf(vb[u].x, p0, a0.x); a0.y = fmaf(vb[u].y, p0, a0.y);
                    a0.z = fmaf(vb[u].z, p0, a0.z); a0.w = fmaf(vb[u].w, p0, a0.w);
                    a1.x = fmaf(vb[u].x, p1, a1.x); a1.y = fmaf(vb[u].y, p1, a1.y);
                    a1.z = fmaf(vb[u].z, p1, a1.z); a1.w = fmaf(vb[u].w, p1, a1.w);
                }
            }
        } else {
            const float* vbase = vn + (size_t)bh * QQ * DHH;
            for (int kk = 0; kk < 16; ++kk) {
                float4 v4 = *(const float4*)(vbase + (size_t)kk * DHH + d4);
                float p0 = p[q0 * 256 + kk];
                float p1 = p[(q0 + 8) * 256 + kk];
                a0.x = fmaf(v4.x, p0, a0.x); a0.y = fmaf(v4.y, p0, a0.y);
                a0.z = fmaf(v4.z, p0, a0.z); a0.w = fmaf(v4.w, p0, a0.w);
                a1.x = fmaf(v4.x, p1, a1.x); a1.y = fmaf(v4.y, p1, a1.y);
                a1.z = fmaf(v4.z, p1, a1.z); a1.w = fmaf(v4.w, p1, a1.w);
            }
        }
        size_t pb = ((size_t)ch * BH + bh) * (QQ * DHH);
        *(float4*)(part + pb + q0 * DHH + d4) = a0;
        *(float4*)(part + pb + (q0 + 8) * DHH + d4) = a1;
    } else {
        int k = (bx - 1056) * 256 + tid;
        if (k >= KK) return;
        rank[k] = 0;
        double t = 0.0;
        for (int bh = 0; bh < BH; ++bh)
            t += exp(sc[(size_t)bh * KK + k] - m64[bh]) / z64[bh];
        double imp = t / 32.0;
        if (k == KK - 1) imp = INFINITY;
        unsigned long long bits = (unsigned long long)__double_as_longlong(imp);
        keys[k] = (bits & ~0x3FFFull) | (unsigned long long)k;
    }
}

// ---------------------------------------------------------------- fused: PV reduce (0-255) + rankpart (256-519)
__global__ __launch_bounds__(256) void fused_pvred_rankpart_kernel(
    const float* __restrict__ part, float* __restrict__ oattn,
    const unsigned long long* __restrict__ keys, int* __restrict__ rank)
{
    int bx = blockIdx.x, tid = threadIdx.x;
    __shared__ unsigned long long chnk[1026];
    if (bx < 256) {
        int e = bx * 256 + tid;
        float sa = 0.f, sb = 0.f;
#pragma unroll 8
        for (int ch = 0; ch < 16; ++ch) sa += part[(size_t)ch * 65536 + e];
#pragma unroll 8
        for (int ch = 16; ch < 33; ++ch) sb += part[(size_t)ch * 65536 + e];
        float s = sa + sb;
        int bh = e >> 11, rem = e & 2047, q = rem >> 7, d = rem & 127;
        int b = bh >> 4, h = bh & 15;
        oattn[((size_t)(b * QQ + q)) * DD + h * DHH + d] = s;
    } else {
        int idx = bx - 256;
        int xb = idx % 33, yb = idx / 33;
        int gid = xb * 256 + tid;
        int base = yb * 1026;
        for (int i = tid; i < 1026; i += 256) chnk[i] = keys[base + i];
        __syncthreads();
        if (gid >= KK) return;
        unsigned long long mykey = keys[gid];
        int cnt = 0;
#pragma unroll 6
        for (int i = 0; i < 1026; ++i) cnt += (chnk[i] < mykey) ? 1 : 0;
        atomicAdd(&rank[gid], cnt);
    }
}

// ---------------------------------------------------------------- fused: Wo GEMM (0-255) + rankwrite (256-288)
__global__ __launch_bounds__(256) void fused_wogemm_rankwrite_kernel(
    const float* __restrict__ A, const float* __restrict__ wo,
    float* __restrict__ part,
    const unsigned long long* __restrict__ keys, const int* __restrict__ rank,
    float* __restrict__ outp)
{
    int bx = blockIdx.x, tid = threadIdx.x;
    __shared__ __align__(16) float xs[32 * 32];
    if (bx < 256) {
        int cc = bx & 3, kc = bx >> 2;
        int col0 = cc * 512 + tid;
        int d0 = kc * 32;
        for (int i = tid; i < 32 * 32; i += 256) {
            int r = i >> 5, d = i & 31;
            xs[i] = A[(size_t)r * DD + d0 + d];
        }
        __syncthreads();
        float acc0[32], acc1[32];
#pragma unroll
        for (int r = 0; r < 32; ++r) { acc0[r] = 0.f; acc1[r] = 0.f; }
        const float* wp = wo + (size_t)d0 * DD + col0;
        for (int d = 0; d < 32; d += 8) {
            float wb0[8], wb1[8];
#pragma unroll
            for (int u = 0; u < 8; ++u) {
                wb0[u] = wp[(size_t)(d + u) * DD];
                wb1[u] = wp[(size_t)(d + u) * DD + 256];
            }
#pragma unroll
            for (int r = 0; r < 32; ++r) {
                const float4 x0 = *(const float4*)(xs + r * 32 + d);
                const float4 x1 = *(const float4*)(xs + r * 32 + d + 4);
                float a = acc0[r], b = acc1[r];
                a = fmaf(x0.x, wb0[0], a);  b = fmaf(x0.x, wb1[0], b);
                a = fmaf(x0.y, wb0[1], a);  b = fmaf(x0.y, wb1[1], b);
                a = fmaf(x0.z, wb0[2], a);  b = fmaf(x0.z, wb1[2], b);
                a = fmaf(x0.w, wb0[3], a);  b = fmaf(x0.w, wb1[3], b);
                a = fmaf(x1.x, wb0[4], a);  b = fmaf(x1.x, wb1[4], b);
                a = fmaf(x1.y, wb0[5], a);  b = fmaf(x1.y, wb1[5], b);
                a = fmaf(x1.z, wb0[6], a);  b = fmaf(x1.z, wb1[6], b);
                a = fmaf(x1.w, wb0[7], a);  b = fmaf(x1.w, wb1[7], b);
                acc0[r] = a; acc1[r] = b;
            }
        }
#pragma unroll
        for (int r = 0; r < 32; ++r) {
            part[((size_t)(kc * 32 + r)) * DD + col0] = acc0[r];
            part[((size_t)(kc * 32 + r)) * DD + col0 + 256] = acc1[r];
        }
    } else {
        int gid = (bx - 256) * 256 + tid;
        if (gid >= KK) return;
        int r = rank[gid];
        if (r < NPRUNE)
            outp[r] = (float)(unsigned)(keys[gid] & 0x3FFFu);
    }
}

// ---------------------------------------------------------------- Wo reduce + residual (dual 32+32)
__global__ __launch_bounds__(256) void reduce_wo_kernel(
    const float* __restrict__ part, const float* __restrict__ resid,
    float* __restrict__ hbuf)
{
    int e = blockIdx.x * 256 + threadIdx.x;
    float sa = 0.f, sb = 0.f;
#pragma unroll 8
    for (int kc = 0; kc < 32; ++kc) {
        sa += part[(size_t)kc * 65536 + e];
        sb += part[(size_t)(kc + 32) * 65536 + e];
    }
    hbuf[e] = resid[e] + (sa + sb);
}

// ---------------------------------------------------------------- fused gate+up reduce + silu
__global__ __launch_bounds__(256) void reduce_gateup_silu_kernel(
    const float* __restrict__ part, float* __restrict__ act)
{
    int e = blockIdx.x * 256 + threadIdx.x;
    float ga = 0.f, gb = 0.f, ua = 0.f, ub = 0.f;
#pragma unroll 8
    for (int kc = 0; kc < 16; ++kc) {
        ga += part[(size_t)kc * 180224 + e];
        gb += part[(size_t)(kc + 16) * 180224 + e];
        ua += part[(size_t)(kc + 32) * 180224 + e];
        ub += part[(size_t)(kc + 48) * 180224 + e];
    }
    float g = ga + gb, u = ua + ub;
    float sg = g / (1.f + expf(-g));
    act[e] = sg * u;
}

// ---------------------------------------------------------------- down reduce + residual (dual 88+88)
__global__ __launch_bounds__(256) void reduce_down_kernel(
    const float* __restrict__ part, const float* __restrict__ hbuf,
    float* __restrict__ out)
{
    int e = blockIdx.x * 256 + threadIdx.x;
    float sa = 0.f, sb = 0.f;
#pragma unroll 8
    for (int kc = 0; kc < 88; ++kc) {
        sa += part[(size_t)kc * 65536 + e];
        sb += part[(size_t)(kc + 88) * 65536 + e];
    }
    out[e] = hbuf[e] + (sa + sb);
}

// ================================================================ launch
extern "C" void kernel_launch(void* const* d_in, const int* in_sizes, int n_in,
                              void* d_out, int out_size, void* d_ws, size_t ws_size,
                              hipStream_t stream)
{
    const float* hidden = (const float*)d_in[0];
    const float* past_k = (const float*)d_in[1];
    const float* past_v = (const float*)d_in[2];
    const float* wq     = (const float*)d_in[3];
    const float* wk     = (const float*)d_in[4];
    const float* wv     = (const float*)d_in[5];
    const float* wo     = (const float*)d_in[6];
    const float* wgate  = (const float*)d_in[7];
    const float* wup    = (const float*)d_in[8];
    const float* wdown  = (const float*)d_in[9];
    const float* n1w    = (const float*)d_in[10];
    const float* n2w    = (const float*)d_in[11];

    float* out_hidden = (float*)d_out;
    float* attn = out_hidden + (size_t)RR * DD;
    float* out_prune = attn + (size_t)BH * QQ * KK;
    float* ws = (float*)d_ws;
    double* p64part = (double*)(ws + OFF_P64P);
    double* f64 = (double*)(ws + OFF_F64);
    double* x64 = f64 + D_X64;
    double* k64 = f64 + D_K64;
    double* q64 = f64 + D_Q64;
    double* m64 = f64 + D_M64;
    double* z64 = f64 + D_Z64;
    double* sc64 = f64 + D_SC;
    unsigned long long* keys = (unsigned long long*)(f64 + D_KEYS);
    int* rank = (int*)(ws + OFF_RANK);

    // 1. rmsnorm1 + rms32mix
    fused_rms_kernel<<<dim3(64), dim3(256), 0, stream>>>(hidden, n1w, ws + OFF_X, x64);

    // 2. QKV GEMM + proj64_part
    fused_qkv_p64_kernel<<<dim3(1024), dim3(256), 0, stream>>>(
        ws + OFF_X, wq, wk, wv, ws + OFF_UNION, x64, p64part);

    // 3. QKV reduce+RoPE + proj64 reduce+RoPE
    fused_reduce_kernel<<<dim3(528), dim3(256), 0, stream>>>(
        ws + OFF_UNION, ws + OFF_QR, ws + OFF_KN, ws + OFF_VN, p64part, k64, q64);

    // 4. scores (f32 + fused f64)
    scores_kernel<<<dim3(BH, 17), dim3(256), 0, stream>>>(
        ws + OFF_QR, past_k, ws + OFF_KN, attn, q64, k64, sc64);

    // 5. rowstats f32 (512) + f64 (32) fused
    fused_rowstats_kernel<<<dim3(544), dim3(256), 0, stream>>>(
        attn, ws + OFF_ROWM, ws + OFF_ROWZ, sc64, m64, z64);

    // 6. PV + impkeys
    fused_pv_impkeys_kernel<<<dim3(1089), dim3(256), 0, stream>>>(
        attn, past_v, ws + OFF_VN, ws + OFF_ROWM, ws + OFF_ROWZ, ws + OFF_UNION,
        sc64, m64, z64, keys, rank);

    // 7. PV reduce + rankpart
    fused_pvred_rankpart_kernel<<<dim3(520), dim3(256), 0, stream>>>(
        ws + OFF_UNION, ws + OFF_OATTN, keys, rank);

    // 8. Wo GEMM + rankwrite
    fused_wogemm_rankwrite_kernel<<<dim3(289), dim3(256), 0, stream>>>(
        ws + OFF_OATTN, wo, ws + OFF_UNION, keys, rank, out_prune);

    // 9. + residual
    reduce_wo_kernel<<<dim3(256), dim3(256), 0, stream>>>(ws + OFF_UNION, hidden, ws + OFF_H);

    // 10. rmsnorm2
    rmsnorm_kernel<<<dim3(RR), dim3(256), 0, stream>>>(ws + OFF_H, n2w, ws + OFF_Y);

    // 11. gate+up GEMM + fused reduce+silu
    gemm32c2<64><<<dim3(11, 32, 2), dim3(256), 0, stream>>>(
        ws + OFF_Y, wgate, wup, wup, ws + OFF_UNION, DD, FF, (size_t)32 * 180224);
    reduce_gateup_silu_kernel<<<dim3(704), dim3(256), 0, stream>>>(
        ws + OFF_UNION, ws + OFF_ACT);

    // 12. down GEMM + reduce
    gemm32c2<32><<<dim3(4, 176, 1), dim3(256), 0, stream>>>(
        ws + OFF_ACT, wdown, wdown, wdown, ws + OFF_UNION, FF, DD, 0);
    reduce_down_kernel<<<dim3(256), dim3(256), 0, stream>>>(
        ws + OFF_UNION, ws + OFF_H, out_hidden);
}